// Round 14
// baseline (162.229 us; speedup 1.0000x reference)
//
#include <hip/hip_runtime.h>

// HetGNN fused kernel, round 28: fuse mlp6 layer-1 back into MFMA.
// R27 profile: VALU-issue-bound (46.5% busy, 65K cy/SIMD) at 2 waves/SIMD;
// MFMA only 22%. Largest VALU block: build_h (~432 insts/chain-it) doing
// relu(aP + eP_nbr) in unpack/add/fmax/repack glue. This round inverts the
// aP/eP factoring: mlp6 layer-1 is computed per neighbor tile as a K128
// MFMA, B = {own a-frags, neighbor e-frags}:
//  - a-frags: lane's own A.f0/f1 (a is k- and bp-independent) -- no gather;
//  - e_nbr-frags: ldN rows 16q+re of an e-FRAGMENT tile (same verified
//    addressing as R27's ev reads); the tile is written with 2 plain
//    ds_write_b128 (frags are already row-layout, zero pack VALU);
//  - w61 is already staged in the K128 fi<48 format.
// Deleted: aP pass, scatter_aP, eP pass, build_h (-456 VALU/chain-it).
// Added: 1 scatter + 2 gathers per j (+96 VALU/it) and +40 MFMA/chain-it
// (the 22%-utilized matrix pipe absorbs it).
// The e-tile (+2.2KB/wave/chain) forces SINGLE chain, PPW=4 (dual would be
// 170K LDS > 160K): sAct 8 x 4352B = 34.8K, total 135.1K, 1 block/CU.
// Weight ds_reads double vs dual-chain (~1% issue, R18 showed dual~=single).
// VGPR drops to ~90-100: no-spill with margin.

typedef unsigned short u16;
typedef unsigned int   u32;
typedef __attribute__((ext_vector_type(8))) short short8_t;
typedef __attribute__((ext_vector_type(2))) short short2v;
typedef __attribute__((ext_vector_type(4))) float floatx4;

#define LDSFENCE() asm volatile("" ::: "memory")

// u16 offsets of each matrix's fragment block inside sW (fi*512 ordering).
// 96 frags: w51(16) w61(16) w71(16) w52(8) w53(8) w62(8) w63(8) w72(8) w73(8).
#define OFF_W51 0
#define OFF_W61 8192
#define OFF_W71 16384
#define OFF_W52 24576
#define OFF_W53 28672
#define OFF_W62 32768
#define OFF_W63 36864
#define OFF_W72 40960
#define OFF_W73 45056
#define WS_U16  49152

// f32 offsets inside the sConst LDS table.
#define CB51 0
#define CB52 64
#define CB53 128
#define CB61 192
#define CB62 256
#define CB63 320
#define CB71 384
#define CB72 448
#define CB73 512
#define CWPO 576
#define CBPO 704
#define CWPA 768
#define CBPA 832
#define CWPE 896
#define CBPE 1024
#define CSZ  1088

// per-wave tiles: BUF (T1/agg, 128 rows) + eT (e frags, 128 rows)
#define BUF_U16 1088
#define ET_U16  1088
#define PW_U16  2176

struct Params {
  const float *ap, *ef;
  const float *wpa, *bpa, *wpe, *bpe;
  const float *w51, *b51, *w52, *b52, *w53, *b53;
  const float *w61, *b61, *w62, *b62, *w63, *b63;
  const float *w71, *b71, *w72, *b72, *w73, *b73;
  const float *wpost, *bpost;
  float *out;
  int gtot;
};

// Pack two f32 to bf16 pair: round-half-up via +0x8000, then one byte-perm.
// Low half = first arg. (PROVEN form; v_cvt_pk_bf16_f32 asm fails here.)
__device__ __forceinline__ u32 pk2(float a, float b) {
  const u32 ua = __float_as_uint(a) + 0x8000u;
  const u32 ub = __float_as_uint(b) + 0x8000u;
  return __builtin_amdgcn_perm(ub, ua, 0x07060302u);  // {ub[31:16], ua[31:16]}
}
// packed int16 max: exact bf16-max in our use because the final max-with-0
// (deferred relu) dominates any mis-ordered negative intermediate.
__device__ __forceinline__ u32 pkmax(u32 a, u32 b) {
  const short2v r = __builtin_elementwise_max(__builtin_bit_cast(short2v, a),
                                              __builtin_bit_cast(short2v, b));
  return __builtin_bit_cast(u32, r);
}
__device__ __forceinline__ float sel4(int i, float x0, float x1, float x2, float x3) {
  const float lo = (i & 1) ? x1 : x0;
  const float hi = (i & 1) ? x3 : x2;
  return (i & 2) ? hi : lo;
}

__device__ __forceinline__ floatx4 mfma16(short8_t a, short8_t b, floatx4 c) {
  return __builtin_amdgcn_mfma_f32_16x16x32_bf16(a, b, c, 0, 0, 0);
}
// tile row start (u16 index): row*16B + 16B skew per 16 rows
__device__ __forceinline__ int rowN(int row) { return row * 8 + (row >> 4) * 8; }
// tile gather: loads through uint4 (int family) so it orders against the
// u32 scatters under TBAA.
__device__ __forceinline__ short8_t ldN(const u16* buf, int row) {
  const uint4 v = *(const uint4*)(buf + rowN(row));
  return __builtin_bit_cast(short8_t, v);
}
// frag -> tile row direct write (no pack: frags are already row-layout).
__device__ __forceinline__ void writeF(u16* buf, int row, short8_t f) {
  *(uint4*)(buf + rowN(row)) = __builtin_bit_cast(uint4, f);
}

// K=64 layer: frags (t*TS+0, t*TS+1) from sW.
template<int TS>
__device__ __forceinline__ void layerK64R(floatx4* acc, short8_t x0, short8_t x1,
                                          const u16* B, int l) {
#pragma unroll
  for (int t = 0; t < 4; ++t) {
    const short8_t b0 = *(const short8_t*)(B + (t * TS + 0) * 512 + l * 8);
    const short8_t b1 = *(const short8_t*)(B + (t * TS + 1) * 512 + l * 8);
    acc[t] = mfma16(x0, b0, acc[t]);
    acc[t] = mfma16(x1, b1, acc[t]);
  }
}
// K=128 layer (4 activation frags), weights = 16 frags (t*4+h).
__device__ __forceinline__ void layerK128R(floatx4* acc,
                                           short8_t x0, short8_t x1,
                                           short8_t x2, short8_t x3,
                                           const u16* B, int l) {
  const short8_t x[4] = {x0, x1, x2, x3};
#pragma unroll
  for (int t = 0; t < 4; ++t)
#pragma unroll
    for (int h = 0; h < 4; ++h)
      acc[t] = mfma16(x[h], *(const short8_t*)(B + (t * 4 + h) * 512 + l * 8), acc[t]);
}

// pi0 scatter: u32 (tp, r) from lane (q,n) -> row tp*64 + g*16 + 4q + r,
// dword n&3. relu via packed pkmax0. 8 ds_write_b32, 2 lanes/bank.
__device__ __forceinline__ void scatterN_relu(u16* dst, const floatx4* acc, int q, int n) {
  u32* d32 = (u32*)dst;
  const int g = n >> 2, d = n & 3;
#pragma unroll
  for (int tp = 0; tp < 2; ++tp)
#pragma unroll
    for (int r = 0; r < 4; ++r) {
      const int row = tp * 64 + g * 16 + 4 * q + r;
      d32[row * 4 + (row >> 4) * 4 + d] =
          pkmax(pk2(acc[2 * tp + 0][r], acc[2 * tp + 1][r]), 0u);
    }
  LDSFENCE();
}
// scatter of pre-packed u32s (v[tp*4+r]).
__device__ __forceinline__ void scatterN_u32(u16* dst, const u32* v, int q, int n) {
  u32* d32 = (u32*)dst;
  const int g = n >> 2, d = n & 3;
#pragma unroll
  for (int tp = 0; tp < 2; ++tp)
#pragma unroll
    for (int r = 0; r < 4; ++r) {
      const int row = tp * 64 + g * 16 + 4 * q + r;
      d32[row * 4 + (row >> 4) * 4 + d] = v[tp * 4 + r];
    }
  LDSFENCE();
}

__device__ __forceinline__ void init_accL(floatx4* acc, const float* cb, int n) {
#pragma unroll
  for (int t = 0; t < 4; ++t) {
    const float b = cb[16 * t + n];
    floatx4 v; v[0] = b; v[1] = b; v[2] = b; v[3] = b;
    acc[t] = v;
  }
}

struct frag2 { short8_t f0, f1; };

__device__ __forceinline__ frag2 make_a(float apv, int q, const float* sc) {
  frag2 r;
#pragma unroll
  for (int h = 0; h < 2; ++h) {
    const int fb = 32 * h + 8 * q;
    const float4 wa0 = *(const float4*)(sc + CWPA + fb);
    const float4 wa1 = *(const float4*)(sc + CWPA + fb + 4);
    const float4 ba0 = *(const float4*)(sc + CBPA + fb);
    const float4 ba1 = *(const float4*)(sc + CBPA + fb + 4);
    uint4 pa;
    pa.x = pk2(fmaxf(fmaf(apv, wa0.x, ba0.x), 0.f), fmaxf(fmaf(apv, wa0.y, ba0.y), 0.f));
    pa.y = pk2(fmaxf(fmaf(apv, wa0.z, ba0.z), 0.f), fmaxf(fmaf(apv, wa0.w, ba0.w), 0.f));
    pa.z = pk2(fmaxf(fmaf(apv, wa1.x, ba1.x), 0.f), fmaxf(fmaf(apv, wa1.y, ba1.y), 0.f));
    pa.w = pk2(fmaxf(fmaf(apv, wa1.z, ba1.z), 0.f), fmaxf(fmaf(apv, wa1.w, ba1.w), 0.f));
    if (h == 0) r.f0 = __builtin_bit_cast(short8_t, pa);
    else        r.f1 = __builtin_bit_cast(short8_t, pa);
  }
  return r;
}

// Pre-layer: a-frag + e-frags straight into registers (pi0-permuted tables).
__device__ __forceinline__ void prelayer(frag2& A, short8_t& e0, short8_t& e1,
                                         const Params& p, const float* sc,
                                         int g0, int q, int n) {
  const float apv = p.ap[(g0 + (n >> 3)) * 4 + ((n >> 1) & 3)];
  A = make_a(apv, q, sc);
  const float f0 = p.ef[(g0 + (n >> 3)) * 16 + (n & 7) * 2];
  const float f1 = p.ef[(g0 + (n >> 3)) * 16 + (n & 7) * 2 + 1];
#pragma unroll
  for (int h = 0; h < 2; ++h) {
    const int fb = 32 * h + 8 * q;
    const float4 w00 = *(const float4*)(sc + CWPE + fb);
    const float4 w01 = *(const float4*)(sc + CWPE + fb + 4);
    const float4 w10 = *(const float4*)(sc + CWPE + 64 + fb);
    const float4 w11 = *(const float4*)(sc + CWPE + 64 + fb + 4);
    const float4 be0 = *(const float4*)(sc + CBPE + fb);
    const float4 be1 = *(const float4*)(sc + CBPE + fb + 4);
    uint4 pe;
    pe.x = pk2(fmaxf(fmaf(f0, w00.x, fmaf(f1, w10.x, be0.x)), 0.f),
               fmaxf(fmaf(f0, w00.y, fmaf(f1, w10.y, be0.y)), 0.f));
    pe.y = pk2(fmaxf(fmaf(f0, w00.z, fmaf(f1, w10.z, be0.z)), 0.f),
               fmaxf(fmaf(f0, w00.w, fmaf(f1, w10.w, be0.w)), 0.f));
    pe.z = pk2(fmaxf(fmaf(f0, w01.x, fmaf(f1, w11.x, be1.x)), 0.f),
               fmaxf(fmaf(f0, w01.y, fmaf(f1, w11.y, be1.y)), 0.f));
    pe.w = pk2(fmaxf(fmaf(f0, w01.z, fmaf(f1, w11.z, be1.z)), 0.f),
               fmaxf(fmaf(f0, w01.w, fmaf(f1, w11.w, be1.w)), 0.f));
    if (h == 0) e0 = __builtin_bit_cast(short8_t, pe);
    else        e1 = __builtin_bit_cast(short8_t, pe);
  }
}

// Post linear + per-(g,b) L2 row normalization.
__device__ __forceinline__ void epilogue(const floatx4* acc3, const float* sc,
                                         float* out, int g0, int q, int n) {
  float prr[4] = {0.f, 0.f, 0.f, 0.f}, pii[4] = {0.f, 0.f, 0.f, 0.f};
#pragma unroll
  for (int t = 0; t < 4; ++t) {
    const float wr = sc[CWPO + (16 * t + n) * 2];
    const float wi = sc[CWPO + (16 * t + n) * 2 + 1];
#pragma unroll
    for (int r = 0; r < 4; ++r) {
      const float e = fmaxf(acc3[t][r], 0.f);
      prr[r] = fmaf(e, wr, prr[r]);
      pii[r] = fmaf(e, wi, pii[r]);
    }
  }
  const float bpR = sc[CBPO], bpI = sc[CBPO + 1];
#pragma unroll
  for (int r = 0; r < 4; ++r) {
#pragma unroll
    for (int off = 1; off < 16; off <<= 1) {
      prr[r] += __shfl_xor(prr[r], off, 16);
      pii[r] += __shfl_xor(pii[r], off, 16);
    }
    prr[r] += bpR;
    pii[r] += bpI;
  }
  const int r = n >> 1, c = n & 1, rp = r ^ 1;
  const float pr_r  = sel4(r,  prr[0], prr[1], prr[2], prr[3]);
  const float pi_r  = sel4(r,  pii[0], pii[1], pii[2], pii[3]);
  const float pr_rp = sel4(rp, prr[0], prr[1], prr[2], prr[3]);
  const float pi_rp = sel4(rp, pii[0], pii[1], pii[2], pii[3]);
  const float num = c ? pi_r : pr_r;
  const float n2  = pr_r * pr_r + pi_r * pi_r + pr_rp * pr_rp + pi_rp * pi_rp;
  if (n < 8) out[g0 * 16 + (4 * q + r) * 2 + c] = num / sqrtf(n2);
}

#define NBLK 256
#define NWAVE 8
#define PPW  4   // 256 blk * 8 waves * 4 pairs = 8192 pairs = 16384 graphs

__global__ __launch_bounds__(512, 2)
__attribute__((amdgpu_waves_per_eu(2, 2)))
void hetgnn_mfma(Params p) {
  __shared__ __align__(16) u16   sW[WS_U16];            // 96 KB weights
  __shared__ __align__(16) u16   sAct[NWAVE * PW_U16];  // 34 KB: 8 x (BUF|eT)
  __shared__ __align__(16) float sConst[CSZ];           // 4.25 KB

  const int tid  = threadIdx.x;
  const int wave = tid >> 6;
  const int l    = tid & 63;
  const int q    = l >> 4;
  const int n    = l & 15;

  // ---- stage + swizzle weights (f32 global -> bf16 B-frag LDS), 96 frags.
  //      pi0 k-order; K128 mats (incl. w61) use the 2-half formula.
  {
    for (int fi = wave; fi < 96; fi += NWAVE) {   // wave-uniform fi, 12/wave
      int t, h, mi;
      if (fi < 48) { mi = fi >> 4; const int loc = fi & 15; t = loc >> 2; h = loc & 3; }
      else { const int j = fi - 48; mi = 3 + (j >> 3); const int loc = j & 7; t = loc >> 1; h = loc & 1; }
      const float* W =
          (mi == 0) ? p.w51 : (mi == 1) ? p.w61 : (mi == 2) ? p.w71 :
          (mi == 3) ? p.w52 : (mi == 4) ? p.w53 : (mi == 5) ? p.w62 :
          (mi == 6) ? p.w63 : (mi == 7) ? p.w72 : p.w73;
      const int nn = 16 * t + n;
      float w[8];
#pragma unroll
      for (int jj = 0; jj < 8; ++jj) {
        const int kidx = (fi < 48)
            ? 64 * (h >> 1) + 32 * (h & 1) + (jj & 1) * 16 + 4 * q + (jj >> 1)
            : 32 * h + (jj & 1) * 16 + 4 * q + (jj >> 1);
        w[jj] = W[kidx * 64 + nn];
      }
      uint4 o;
      o.x = pk2(w[0], w[1]); o.y = pk2(w[2], w[3]);
      o.z = pk2(w[4], w[5]); o.w = pk2(w[6], w[7]);
      *(uint4*)(sW + fi * 512 + l * 8) = o;
    }
  }
  if (tid < 64) {
    sConst[CB51 + tid] = p.b51[tid];
    sConst[CB52 + tid] = p.b52[tid];
    sConst[CB53 + tid] = p.b53[tid];
    sConst[CB61 + tid] = p.b61[tid];
    sConst[CB62 + tid] = p.b62[tid];
    sConst[CB63 + tid] = p.b63[tid];
    sConst[CB71 + tid] = p.b71[tid];
    sConst[CB72 + tid] = p.b72[tid];
    sConst[CB73 + tid] = p.b73[tid];
    // pre-layer tables permuted to pi0 slot order:
    // slot s holds feat = 32*(s>>5) + (s&1)*16 + 4*((s>>3)&3) + ((s>>1)&3)
    const int feat = 32 * (tid >> 5) + (tid & 1) * 16 + 4 * ((tid >> 3) & 3) + ((tid >> 1) & 3);
    sConst[CWPA + tid] = p.wpa[feat];
    sConst[CBPA + tid] = p.bpa[feat];
    sConst[CBPE + tid] = p.bpe[feat];
  }
  if (tid < 128) {
    sConst[CWPO + tid] = p.wpost[tid];
    const int s = tid & 63;
    const int feat = 32 * (s >> 5) + (s & 1) * 16 + 4 * ((s >> 3) & 3) + ((s >> 1) & 3);
    sConst[CWPE + tid] = p.wpe[(tid >> 6) * 64 + feat];
  }
  if (tid < 2) sConst[CBPO + tid] = p.bpost[tid];
  __syncthreads();

  u16* BUF = sAct + wave * PW_U16;   // T1 / agg tile (overwritten per layer)
  u16* eT  = BUF + BUF_U16;          // e fragment tile (persists per it)

  // neighbor fragment-row offsets per j (within this lane's quarter)
  const int b_ln = (n >> 1) & 3;
  int re[3];
#pragma unroll
  for (int j = 0; j < 3; ++j) {
    const int bp = j + (j >= b_ln);
    re[j] = 16 * q + (n & 8) + 2 * bp + (n & 1);
  }

  const int wslot = blockIdx.x * NWAVE + wave;

#pragma unroll 1
  for (int pi = 0; pi < PPW; ++pi) {
    const int g0 = (wslot * PPW + pi) * 2;   // 2 graphs: g0, g0+1
    if (g0 + 2 > p.gtot) break;

    frag2 A;
    short8_t e0, e1;
    prelayer(A, e0, e1, p, sConst, g0, q, n);

    // ---------------- 2 shared-weight update iterations ----------------
#pragma unroll 1
    for (int it = 0; it < 2; ++it) {
      if (it == 1) {
        e0 = ldN(eT, l); e1 = ldN(eT, 64 + l);   // new e (scattered at it0 end)
      } else {
        writeF(eT, l, e0); writeF(eT, 64 + l, e1);   // e frags -> tile
        LDSFENCE();
      }

      // ---- mlp5 -> m1 (tpair-packed raw bf16; relu deferred to agg) ----
      u32 m1p[8];
      {
        floatx4 acc[4];
        init_accL(acc, sConst + CB51, n);
        layerK128R(acc, A.f0, A.f1, e0, e1, sW + OFF_W51, l);
        scatterN_relu(BUF, acc, q, n);
        short8_t t0 = ldN(BUF, l), t1 = ldN(BUF, 64 + l);
        init_accL(acc, sConst + CB52, n);
        layerK64R<2>(acc, t0, t1, sW + OFF_W52, l);
        scatterN_relu(BUF, acc, q, n);
        t0 = ldN(BUF, l); t1 = ldN(BUF, 64 + l);
        init_accL(acc, sConst + CB53, n);
        layerK64R<2>(acc, t0, t1, sW + OFF_W53, l);
#pragma unroll
        for (int tp = 0; tp < 2; ++tp)
#pragma unroll
          for (int r = 0; r < 4; ++r)
            m1p[tp * 4 + r] = pk2(acc[2 * tp][r], acc[2 * tp + 1][r]);
      }

      // ---- mlp6 -> m2: 3 neighbor tiles, layer-1 fused as K128 MFMA ----
      u32 m2p[8];
#pragma unroll
      for (int j = 0; j < 3; ++j) {
        const short8_t en0 = ldN(eT, re[j]);
        const short8_t en1 = ldN(eT, 64 + re[j]);
        floatx4 acc[4];
        init_accL(acc, sConst + CB61, n);
        layerK128R(acc, A.f0, A.f1, en0, en1, sW + OFF_W61, l);
        scatterN_relu(BUF, acc, q, n);
        short8_t t0 = ldN(BUF, l), t1 = ldN(BUF, 64 + l);
        init_accL(acc, sConst + CB62, n);
        layerK64R<2>(acc, t0, t1, sW + OFF_W62, l);
        scatterN_relu(BUF, acc, q, n);
        t0 = ldN(BUF, l); t1 = ldN(BUF, 64 + l);
        init_accL(acc, sConst + CB63, n);
        layerK64R<2>(acc, t0, t1, sW + OFF_W63, l);
#pragma unroll
        for (int tp = 0; tp < 2; ++tp)
#pragma unroll
          for (int r = 0; r < 4; ++r) {
            const u32 cv = pk2(acc[2 * tp][r], acc[2 * tp + 1][r]);
            const int i = tp * 4 + r;
            m2p[i] = (j == 0) ? cv : pkmax(m2p[i], cv);
          }
      }

      // ---- agg = relu(max(m1[k^1], m2)): k-swap is a register index swap ----
      {
        u32 agp[8];
#pragma unroll
        for (int tp = 0; tp < 2; ++tp)
#pragma unroll
          for (int r = 0; r < 4; ++r)
            agp[tp * 4 + r] = pkmax(pkmax(m1p[tp * 4 + (r ^ 1)], m2p[tp * 4 + r]), 0u);
        scatterN_u32(BUF, agp, q, n);
        short8_t g0f = ldN(BUF, l), g1f = ldN(BUF, 64 + l);
        floatx4 acc[4];
        init_accL(acc, sConst + CB71, n);
        layerK128R(acc, g0f, g1f, e0, e1, sW + OFF_W71, l);
        scatterN_relu(BUF, acc, q, n);
        g0f = ldN(BUF, l); g1f = ldN(BUF, 64 + l);
        init_accL(acc, sConst + CB72, n);
        layerK64R<2>(acc, g0f, g1f, sW + OFF_W72, l);
        scatterN_relu(BUF, acc, q, n);
        g0f = ldN(BUF, l); g1f = ldN(BUF, 64 + l);
        init_accL(acc, sConst + CB73, n);
        layerK64R<2>(acc, g0f, g1f, sW + OFF_W73, l);

        if (it == 0) {
          scatterN_relu(eT, acc, q, n);   // new e -> eT (full-tile overwrite)
        } else {
          epilogue(acc, sConst, p.out, g0, q, n);
        }
      }
    }
  }
}

extern "C" void kernel_launch(void* const* d_in, const int* in_sizes, int n_in,
                              void* d_out, int out_size, void* d_ws, size_t ws_size,
                              hipStream_t stream) {
  Params p;
  p.ap    = (const float*)d_in[0];
  p.ef    = (const float*)d_in[1];
  p.wpa   = (const float*)d_in[2];  p.bpa   = (const float*)d_in[3];
  p.wpe   = (const float*)d_in[4];  p.bpe   = (const float*)d_in[5];
  p.w51   = (const float*)d_in[6];  p.b51   = (const float*)d_in[7];
  p.w52   = (const float*)d_in[8];  p.b52   = (const float*)d_in[9];
  p.w53   = (const float*)d_in[10]; p.b53   = (const float*)d_in[11];
  p.w61   = (const float*)d_in[12]; p.b61   = (const float*)d_in[13];
  p.w62   = (const float*)d_in[14]; p.b62   = (const float*)d_in[15];
  p.w63   = (const float*)d_in[16]; p.b63   = (const float*)d_in[17];
  p.w71   = (const float*)d_in[18]; p.b71   = (const float*)d_in[19];
  p.w72   = (const float*)d_in[20]; p.b72   = (const float*)d_in[21];
  p.w73   = (const float*)d_in[22]; p.b73   = (const float*)d_in[23];
  p.wpost = (const float*)d_in[24]; p.bpost = (const float*)d_in[25];
  p.out   = (float*)d_out;
  p.gtot  = in_sizes[0] / 4;  // G from ap_feat [G,B,1]

  hipLaunchKernelGGL(hetgnn_mfma, dim3(NBLK), dim3(512), 0, stream, p);
}

// Round 15
// 155.770 us; speedup vs baseline: 1.0415x; 1.0415x over previous
//
#include <hip/hip_runtime.h>

// HetGNN fused kernel, round 29: fused mlp6 layer-1 (R28) + dual-chain ILP
// (R27) -- the eT LDS tile replaced by register-space ds_bpermute.
// R28 post-mortem: single chain exposed the ~10 serial scatter->gather LDS
// round-trips per it (VALU 34 / MFMA 20.5, BOTH lower, time UP = latency-
// bound). Dual chain was load-bearing. The dual blocker was LDS (2x eT =
// 170K); but eT's two jobs have LDS-free forms:
//  (a) neighbor e-frag gather: eT row l == lane l's own frags (R28-verified),
//      so en = ds_bpermute(lane 16q+re[j], e0/e1) -- 8 bpermutes/j/chain;
//  (b) it0->it1 new-e handoff: reuse BUF (R27's proven Eb=T1 alias).
// Deleted vs R27: aP pass, scatter_aP, eP pass, build_h (~500 VALU/chain-it).
// Added: +40 MFMA/chain-it (22%-utilized pipe), 24 bpermutes/chain-it.
// Register pressure BELOW R27 (48-reg hoisted hf arrays gone).
// LDS: 96 + 8x(2x1088 u16) + 4.25 = 135.1 KB, 1 block/CU, 2 waves/SIMD.
// Base: 512 thr, (2,2), pk2 pack (cvt_pk falsified), LDSFENCE discipline,
// uint4 gathers, pi0 layout; 256 blk x 8 waves x 2 chains x 2 = 8192 pairs.

typedef unsigned short u16;
typedef unsigned int   u32;
typedef __attribute__((ext_vector_type(8))) short short8_t;
typedef __attribute__((ext_vector_type(2))) short short2v;
typedef __attribute__((ext_vector_type(4))) float floatx4;

#define LDSFENCE() asm volatile("" ::: "memory")

// u16 offsets of each matrix's fragment block inside sW (fi*512 ordering).
// 96 frags: w51(16) w61(16) w71(16) w52(8) w53(8) w62(8) w63(8) w72(8) w73(8).
#define OFF_W51 0
#define OFF_W61 8192
#define OFF_W71 16384
#define OFF_W52 24576
#define OFF_W53 28672
#define OFF_W62 32768
#define OFF_W63 36864
#define OFF_W72 40960
#define OFF_W73 45056
#define WS_U16  49152

// f32 offsets inside the sConst LDS table.
#define CB51 0
#define CB52 64
#define CB53 128
#define CB61 192
#define CB62 256
#define CB63 320
#define CB71 384
#define CB72 448
#define CB73 512
#define CWPO 576
#define CBPO 704
#define CWPA 768
#define CBPA 832
#define CWPE 896
#define CBPE 1024
#define CSZ  1088

// per-wave: 2 chains x BUF (T1/agg/Eb alias, 128 rows skewed -> 1088 u16)
#define BUF_U16 1088
#define PW_U16  2176

struct Params {
  const float *ap, *ef;
  const float *wpa, *bpa, *wpe, *bpe;
  const float *w51, *b51, *w52, *b52, *w53, *b53;
  const float *w61, *b61, *w62, *b62, *w63, *b63;
  const float *w71, *b71, *w72, *b72, *w73, *b73;
  const float *wpost, *bpost;
  float *out;
  int gtot;
};

// Pack two f32 to bf16 pair: round-half-up via +0x8000, then one byte-perm.
// Low half = first arg. (PROVEN form; v_cvt_pk_bf16_f32 asm fails here.)
__device__ __forceinline__ u32 pk2(float a, float b) {
  const u32 ua = __float_as_uint(a) + 0x8000u;
  const u32 ub = __float_as_uint(b) + 0x8000u;
  return __builtin_amdgcn_perm(ub, ua, 0x07060302u);  // {ub[31:16], ua[31:16]}
}
// packed int16 max: exact bf16-max in our use because the final max-with-0
// (deferred relu) dominates any mis-ordered negative intermediate.
__device__ __forceinline__ u32 pkmax(u32 a, u32 b) {
  const short2v r = __builtin_elementwise_max(__builtin_bit_cast(short2v, a),
                                              __builtin_bit_cast(short2v, b));
  return __builtin_bit_cast(u32, r);
}
__device__ __forceinline__ float sel4(int i, float x0, float x1, float x2, float x3) {
  const float lo = (i & 1) ? x1 : x0;
  const float hi = (i & 1) ? x3 : x2;
  return (i & 2) ? hi : lo;
}

__device__ __forceinline__ floatx4 mfma16(short8_t a, short8_t b, floatx4 c) {
  return __builtin_amdgcn_mfma_f32_16x16x32_bf16(a, b, c, 0, 0, 0);
}
// tile row start (u16 index): row*16B + 16B skew per 16 rows
__device__ __forceinline__ int rowN(int row) { return row * 8 + (row >> 4) * 8; }
// tile gather: loads through uint4 (int family) so it orders against the
// u32 scatters under TBAA.
__device__ __forceinline__ short8_t ldN(const u16* buf, int row) {
  const uint4 v = *(const uint4*)(buf + rowN(row));
  return __builtin_bit_cast(short8_t, v);
}
// pull a full fragment from another lane (addr = src_lane*4, wave-wide).
__device__ __forceinline__ short8_t bperm8(int addr, short8_t f) {
  const uint4 v = __builtin_bit_cast(uint4, f);
  uint4 r;
  r.x = (u32)__builtin_amdgcn_ds_bpermute(addr, (int)v.x);
  r.y = (u32)__builtin_amdgcn_ds_bpermute(addr, (int)v.y);
  r.z = (u32)__builtin_amdgcn_ds_bpermute(addr, (int)v.z);
  r.w = (u32)__builtin_amdgcn_ds_bpermute(addr, (int)v.w);
  return __builtin_bit_cast(short8_t, r);
}

// Dual-chain K=64 layer: each B fragment is loaded ONCE and feeds both chains.
template<int TSTRIDE>
__device__ __forceinline__ void layerK64R2(floatx4* aX, floatx4* aY,
                                           short8_t x0, short8_t x1,
                                           short8_t y0, short8_t y1,
                                           const u16* B, int l) {
#pragma unroll
  for (int t = 0; t < 4; ++t) {
    const short8_t b0 = *(const short8_t*)(B + (t * TSTRIDE + 0) * 512 + l * 8);
    const short8_t b1 = *(const short8_t*)(B + (t * TSTRIDE + 1) * 512 + l * 8);
    aX[t] = mfma16(x0, b0, aX[t]);
    aY[t] = mfma16(y0, b0, aY[t]);
    aX[t] = mfma16(x1, b1, aX[t]);
    aY[t] = mfma16(y1, b1, aY[t]);
  }
}

// Dual-chain K=128 layer (4 A-frags per chain), shared B loads.
__device__ __forceinline__ void layerK128R2(floatx4* aX, floatx4* aY,
                                            const short8_t* fx, const short8_t* fy,
                                            const u16* B, int l) {
#pragma unroll
  for (int t = 0; t < 4; ++t)
#pragma unroll
    for (int h = 0; h < 4; ++h) {
      const short8_t b = *(const short8_t*)(B + (t * 4 + h) * 512 + l * 8);
      aX[t] = mfma16(fx[h], b, aX[t]);
      aY[t] = mfma16(fy[h], b, aY[t]);
    }
}

// pi0 scatter: u32 (tp, r) from lane (q,n) -> row tp*64 + g*16 + 4q + r,
// dword n&3. relu via packed pkmax0. 8 ds_write_b32, 2 lanes/bank.
__device__ __forceinline__ void scatterN_relu(u16* dst, const floatx4* acc, int q, int n) {
  u32* d32 = (u32*)dst;
  const int g = n >> 2, d = n & 3;
#pragma unroll
  for (int tp = 0; tp < 2; ++tp)
#pragma unroll
    for (int r = 0; r < 4; ++r) {
      const int row = tp * 64 + g * 16 + 4 * q + r;
      d32[row * 4 + (row >> 4) * 4 + d] =
          pkmax(pk2(acc[2 * tp + 0][r], acc[2 * tp + 1][r]), 0u);
    }
  LDSFENCE();
}
// scatter of pre-packed u32s (v[tp*4+r]).
__device__ __forceinline__ void scatterN_u32(u16* dst, const u32* v, int q, int n) {
  u32* d32 = (u32*)dst;
  const int g = n >> 2, d = n & 3;
#pragma unroll
  for (int tp = 0; tp < 2; ++tp)
#pragma unroll
    for (int r = 0; r < 4; ++r) {
      const int row = tp * 64 + g * 16 + 4 * q + r;
      d32[row * 4 + (row >> 4) * 4 + d] = v[tp * 4 + r];
    }
  LDSFENCE();
}

__device__ __forceinline__ void init_accL(floatx4* acc, const float* cb, int n) {
#pragma unroll
  for (int t = 0; t < 4; ++t) {
    const float b = cb[16 * t + n];
    floatx4 v; v[0] = b; v[1] = b; v[2] = b; v[3] = b;
    acc[t] = v;
  }
}

struct frag2 { short8_t f0, f1; };

__device__ __forceinline__ frag2 make_a(float apv, int q, const float* sc) {
  frag2 r;
#pragma unroll
  for (int h = 0; h < 2; ++h) {
    const int fb = 32 * h + 8 * q;
    const float4 wa0 = *(const float4*)(sc + CWPA + fb);
    const float4 wa1 = *(const float4*)(sc + CWPA + fb + 4);
    const float4 ba0 = *(const float4*)(sc + CBPA + fb);
    const float4 ba1 = *(const float4*)(sc + CBPA + fb + 4);
    uint4 pa;
    pa.x = pk2(fmaxf(fmaf(apv, wa0.x, ba0.x), 0.f), fmaxf(fmaf(apv, wa0.y, ba0.y), 0.f));
    pa.y = pk2(fmaxf(fmaf(apv, wa0.z, ba0.z), 0.f), fmaxf(fmaf(apv, wa0.w, ba0.w), 0.f));
    pa.z = pk2(fmaxf(fmaf(apv, wa1.x, ba1.x), 0.f), fmaxf(fmaf(apv, wa1.y, ba1.y), 0.f));
    pa.w = pk2(fmaxf(fmaf(apv, wa1.z, ba1.z), 0.f), fmaxf(fmaf(apv, wa1.w, ba1.w), 0.f));
    if (h == 0) r.f0 = __builtin_bit_cast(short8_t, pa);
    else        r.f1 = __builtin_bit_cast(short8_t, pa);
  }
  return r;
}

// Pre-layer for one chain (tables are pi0-permuted at staging).
__device__ __forceinline__ void prelayer(frag2& A, short8_t& e0, short8_t& e1,
                                         const Params& p, const float* sc,
                                         int g0, int q, int n) {
  const float apv = p.ap[(g0 + (n >> 3)) * 4 + ((n >> 1) & 3)];
  A = make_a(apv, q, sc);
  const float f0 = p.ef[(g0 + (n >> 3)) * 16 + (n & 7) * 2];
  const float f1 = p.ef[(g0 + (n >> 3)) * 16 + (n & 7) * 2 + 1];
#pragma unroll
  for (int h = 0; h < 2; ++h) {
    const int fb = 32 * h + 8 * q;
    const float4 w00 = *(const float4*)(sc + CWPE + fb);
    const float4 w01 = *(const float4*)(sc + CWPE + fb + 4);
    const float4 w10 = *(const float4*)(sc + CWPE + 64 + fb);
    const float4 w11 = *(const float4*)(sc + CWPE + 64 + fb + 4);
    const float4 be0 = *(const float4*)(sc + CBPE + fb);
    const float4 be1 = *(const float4*)(sc + CBPE + fb + 4);
    uint4 pe;
    pe.x = pk2(fmaxf(fmaf(f0, w00.x, fmaf(f1, w10.x, be0.x)), 0.f),
               fmaxf(fmaf(f0, w00.y, fmaf(f1, w10.y, be0.y)), 0.f));
    pe.y = pk2(fmaxf(fmaf(f0, w00.z, fmaf(f1, w10.z, be0.z)), 0.f),
               fmaxf(fmaf(f0, w00.w, fmaf(f1, w10.w, be0.w)), 0.f));
    pe.z = pk2(fmaxf(fmaf(f0, w01.x, fmaf(f1, w11.x, be1.x)), 0.f),
               fmaxf(fmaf(f0, w01.y, fmaf(f1, w11.y, be1.y)), 0.f));
    pe.w = pk2(fmaxf(fmaf(f0, w01.z, fmaf(f1, w11.z, be1.z)), 0.f),
               fmaxf(fmaf(f0, w01.w, fmaf(f1, w11.w, be1.w)), 0.f));
    if (h == 0) e0 = __builtin_bit_cast(short8_t, pe);
    else        e1 = __builtin_bit_cast(short8_t, pe);
  }
}

// Post linear + per-(g,b) L2 row normalization for one chain.
__device__ __forceinline__ void epilogue(const floatx4* acc3, const float* sc,
                                         float* out, int g0, int q, int n, bool ok) {
  float prr[4] = {0.f, 0.f, 0.f, 0.f}, pii[4] = {0.f, 0.f, 0.f, 0.f};
#pragma unroll
  for (int t = 0; t < 4; ++t) {
    const float wr = sc[CWPO + (16 * t + n) * 2];
    const float wi = sc[CWPO + (16 * t + n) * 2 + 1];
#pragma unroll
    for (int r = 0; r < 4; ++r) {
      const float e = fmaxf(acc3[t][r], 0.f);
      prr[r] = fmaf(e, wr, prr[r]);
      pii[r] = fmaf(e, wi, pii[r]);
    }
  }
  const float bpR = sc[CBPO], bpI = sc[CBPO + 1];
#pragma unroll
  for (int r = 0; r < 4; ++r) {
#pragma unroll
    for (int off = 1; off < 16; off <<= 1) {
      prr[r] += __shfl_xor(prr[r], off, 16);
      pii[r] += __shfl_xor(pii[r], off, 16);
    }
    prr[r] += bpR;
    pii[r] += bpI;
  }
  const int r = n >> 1, c = n & 1, rp = r ^ 1;
  const float pr_r  = sel4(r,  prr[0], prr[1], prr[2], prr[3]);
  const float pi_r  = sel4(r,  pii[0], pii[1], pii[2], pii[3]);
  const float pr_rp = sel4(rp, prr[0], prr[1], prr[2], prr[3]);
  const float pi_rp = sel4(rp, pii[0], pii[1], pii[2], pii[3]);
  const float num = c ? pi_r : pr_r;
  const float n2  = pr_r * pr_r + pi_r * pi_r + pr_rp * pr_rp + pi_rp * pi_rp;
  if (ok && n < 8) out[g0 * 16 + (4 * q + r) * 2 + c] = num / sqrtf(n2);
}

#define NBLK 256
#define NWAVE 8
#define PPW  2   // 256 blk * 8 waves * 2 chains * 2 = 8192 pairs = 16384 graphs

__global__ __launch_bounds__(512, 2)
__attribute__((amdgpu_waves_per_eu(2, 2)))
void hetgnn_mfma(Params p) {
  __shared__ __align__(16) u16   sW[WS_U16];            // 96 KB weights
  __shared__ __align__(16) u16   sAct[NWAVE * PW_U16];  // 34 KB: 8 x 2 x BUF
  __shared__ __align__(16) float sConst[CSZ];           // 4.25 KB

  const int tid  = threadIdx.x;
  const int wave = tid >> 6;
  const int l    = tid & 63;
  const int q    = l >> 4;
  const int n    = l & 15;

  // ---- stage + swizzle weights (f32 global -> bf16 B-frag LDS), 96 frags.
  //      pi0 k-order; K128 mats (w51/w61/w71) use the 2-half formula.
  {
    for (int fi = wave; fi < 96; fi += NWAVE) {   // wave-uniform fi, 12/wave
      int t, h, mi;
      if (fi < 48) { mi = fi >> 4; const int loc = fi & 15; t = loc >> 2; h = loc & 3; }
      else { const int j = fi - 48; mi = 3 + (j >> 3); const int loc = j & 7; t = loc >> 1; h = loc & 1; }
      const float* W =
          (mi == 0) ? p.w51 : (mi == 1) ? p.w61 : (mi == 2) ? p.w71 :
          (mi == 3) ? p.w52 : (mi == 4) ? p.w53 : (mi == 5) ? p.w62 :
          (mi == 6) ? p.w63 : (mi == 7) ? p.w72 : p.w73;
      const int nn = 16 * t + n;
      float w[8];
#pragma unroll
      for (int jj = 0; jj < 8; ++jj) {
        const int kidx = (fi < 48)
            ? 64 * (h >> 1) + 32 * (h & 1) + (jj & 1) * 16 + 4 * q + (jj >> 1)
            : 32 * h + (jj & 1) * 16 + 4 * q + (jj >> 1);
        w[jj] = W[kidx * 64 + nn];
      }
      uint4 o;
      o.x = pk2(w[0], w[1]); o.y = pk2(w[2], w[3]);
      o.z = pk2(w[4], w[5]); o.w = pk2(w[6], w[7]);
      *(uint4*)(sW + fi * 512 + l * 8) = o;
    }
  }
  if (tid < 64) {
    sConst[CB51 + tid] = p.b51[tid];
    sConst[CB52 + tid] = p.b52[tid];
    sConst[CB53 + tid] = p.b53[tid];
    sConst[CB61 + tid] = p.b61[tid];
    sConst[CB62 + tid] = p.b62[tid];
    sConst[CB63 + tid] = p.b63[tid];
    sConst[CB71 + tid] = p.b71[tid];
    sConst[CB72 + tid] = p.b72[tid];
    sConst[CB73 + tid] = p.b73[tid];
    // pre-layer tables permuted to pi0 slot order:
    // slot s holds feat = 32*(s>>5) + (s&1)*16 + 4*((s>>3)&3) + ((s>>1)&3)
    const int feat = 32 * (tid >> 5) + (tid & 1) * 16 + 4 * ((tid >> 3) & 3) + ((tid >> 1) & 3);
    sConst[CWPA + tid] = p.wpa[feat];
    sConst[CBPA + tid] = p.bpa[feat];
    sConst[CBPE + tid] = p.bpe[feat];
  }
  if (tid < 128) {
    sConst[CWPO + tid] = p.wpost[tid];
    const int s = tid & 63;
    const int feat = 32 * (s >> 5) + (s & 1) * 16 + 4 * ((s >> 3) & 3) + ((s >> 1) & 3);
    sConst[CWPE + tid] = p.wpe[(tid >> 6) * 64 + feat];
  }
  if (tid < 2) sConst[CBPO + tid] = p.bpost[tid];
  __syncthreads();

  u16* BUF0 = sAct + wave * PW_U16;   // chain X: T1 = agg = Eb alias
  u16* BUF1 = BUF0 + BUF_U16;         // chain Y

  // neighbor source-lane byte addresses per j (bpermute pulls within wave)
  const int b_ln = (n >> 1) & 3;
  int vnb[3];
#pragma unroll
  for (int j = 0; j < 3; ++j) {
    const int bp = j + (j >= b_ln);
    vnb[j] = (16 * q + (n & 8) + 2 * bp + (n & 1)) << 2;
  }

  const int wslot = blockIdx.x * NWAVE + wave;

#pragma unroll 1
  for (int pi = 0; pi < PPW; ++pi) {
    const int g0X = (wslot * 4 + 2 * pi) * 2;   // chain X: graphs g0X, g0X+1
    const int g0Y = g0X + 2;                    // chain Y: graphs g0Y, g0Y+1
    if (g0X + 2 > p.gtot) break;
    const bool okY = (g0Y + 2 <= p.gtot);
    const int gY  = okY ? g0Y : g0X;            // safe index for loads

    // ---------------- pre-layer, both chains ----------------
    frag2 AX, AY;
    short8_t ex0, ex1, ey0, ey1;
    prelayer(AX, ex0, ex1, p, sConst, g0X, q, n);
    prelayer(AY, ey0, ey1, p, sConst, gY,  q, n);

    // ---------------- 2 shared-weight update iterations ----------------
#pragma unroll 1
    for (int it = 0; it < 2; ++it) {
      if (it == 1) {
        ex0 = ldN(BUF0, l); ex1 = ldN(BUF0, 64 + l);   // new e from it0
        ey0 = ldN(BUF1, l); ey1 = ldN(BUF1, 64 + l);
      }

      // ---- mlp5 -> m1 (tpair-packed raw bf16; relu deferred to agg) ----
      u32 m1pX[8], m1pY[8];
      {
        floatx4 aX[4], aY[4];
        init_accL(aX, sConst + CB51, n); init_accL(aY, sConst + CB51, n);
        const short8_t fx[4] = {AX.f0, AX.f1, ex0, ex1};
        const short8_t fy[4] = {AY.f0, AY.f1, ey0, ey1};
        layerK128R2(aX, aY, fx, fy, sW + OFF_W51, l);
        scatterN_relu(BUF0, aX, q, n);
        scatterN_relu(BUF1, aY, q, n);
        floatx4 bX[4], bY[4];
        init_accL(bX, sConst + CB52, n); init_accL(bY, sConst + CB52, n);
        {
          const short8_t gx0 = ldN(BUF0, l), gx1 = ldN(BUF0, 64 + l);
          const short8_t gy0 = ldN(BUF1, l), gy1 = ldN(BUF1, 64 + l);
          layerK64R2<2>(bX, bY, gx0, gx1, gy0, gy1, sW + OFF_W52, l);
        }
        scatterN_relu(BUF0, bX, q, n);
        scatterN_relu(BUF1, bY, q, n);
        floatx4 cX[4], cY[4];
        init_accL(cX, sConst + CB53, n); init_accL(cY, sConst + CB53, n);
        {
          const short8_t gx0 = ldN(BUF0, l), gx1 = ldN(BUF0, 64 + l);
          const short8_t gy0 = ldN(BUF1, l), gy1 = ldN(BUF1, 64 + l);
          layerK64R2<2>(cX, cY, gx0, gx1, gy0, gy1, sW + OFF_W53, l);
        }
#pragma unroll
        for (int tp = 0; tp < 2; ++tp)
#pragma unroll
          for (int r = 0; r < 4; ++r) {
            m1pX[tp * 4 + r] = pk2(cX[2 * tp][r], cX[2 * tp + 1][r]);
            m1pY[tp * 4 + r] = pk2(cY[2 * tp][r], cY[2 * tp + 1][r]);
          }
      }

      // ---- mlp6 -> m2: 3 neighbor tiles, layer-1 fused as K128 MFMA,
      //      neighbor e-frags pulled by ds_bpermute (no LDS tile) ----
      u32 m2pX[8], m2pY[8];
#pragma unroll
      for (int j = 0; j < 3; ++j) {
        const short8_t enX0 = bperm8(vnb[j], ex0);
        const short8_t enX1 = bperm8(vnb[j], ex1);
        const short8_t enY0 = bperm8(vnb[j], ey0);
        const short8_t enY1 = bperm8(vnb[j], ey1);
        floatx4 uX[4], uY[4];
        init_accL(uX, sConst + CB61, n); init_accL(uY, sConst + CB61, n);
        {
          const short8_t fx[4] = {AX.f0, AX.f1, enX0, enX1};
          const short8_t fy[4] = {AY.f0, AY.f1, enY0, enY1};
          layerK128R2(uX, uY, fx, fy, sW + OFF_W61, l);
        }
        scatterN_relu(BUF0, uX, q, n);
        scatterN_relu(BUF1, uY, q, n);
        floatx4 vX[4], vY[4];
        init_accL(vX, sConst + CB62, n); init_accL(vY, sConst + CB62, n);
        {
          const short8_t gx0 = ldN(BUF0, l), gx1 = ldN(BUF0, 64 + l);
          const short8_t gy0 = ldN(BUF1, l), gy1 = ldN(BUF1, 64 + l);
          layerK64R2<2>(vX, vY, gx0, gx1, gy0, gy1, sW + OFF_W62, l);
        }
        scatterN_relu(BUF0, vX, q, n);
        scatterN_relu(BUF1, vY, q, n);
        floatx4 wX[4], wY[4];
        init_accL(wX, sConst + CB63, n); init_accL(wY, sConst + CB63, n);
        {
          const short8_t gx0 = ldN(BUF0, l), gx1 = ldN(BUF0, 64 + l);
          const short8_t gy0 = ldN(BUF1, l), gy1 = ldN(BUF1, 64 + l);
          layerK64R2<2>(wX, wY, gx0, gx1, gy0, gy1, sW + OFF_W63, l);
        }
#pragma unroll
        for (int tp = 0; tp < 2; ++tp)
#pragma unroll
          for (int r = 0; r < 4; ++r) {
            const u32 cXv = pk2(wX[2 * tp][r], wX[2 * tp + 1][r]);
            const u32 cYv = pk2(wY[2 * tp][r], wY[2 * tp + 1][r]);
            const int i = tp * 4 + r;
            m2pX[i] = (j == 0) ? cXv : pkmax(m2pX[i], cXv);
            m2pY[i] = (j == 0) ? cYv : pkmax(m2pY[i], cYv);
          }
      }

      // ---- agg = relu(max(m1[k^1], m2)): k-swap is a register index swap ----
      {
        u32 agX[8], agY[8];
#pragma unroll
        for (int tp = 0; tp < 2; ++tp)
#pragma unroll
          for (int r = 0; r < 4; ++r) {
            const int i = tp * 4 + r;
            agX[i] = pkmax(pkmax(m1pX[tp * 4 + (r ^ 1)], m2pX[i]), 0u);
            agY[i] = pkmax(pkmax(m1pY[tp * 4 + (r ^ 1)], m2pY[i]), 0u);
          }
        scatterN_u32(BUF0, agX, q, n);
        scatterN_u32(BUF1, agY, q, n);
        floatx4 aX[4], aY[4];
        init_accL(aX, sConst + CB71, n); init_accL(aY, sConst + CB71, n);
        {
          const short8_t gx0 = ldN(BUF0, l), gx1 = ldN(BUF0, 64 + l);
          const short8_t gy0 = ldN(BUF1, l), gy1 = ldN(BUF1, 64 + l);
          const short8_t fx[4] = {gx0, gx1, ex0, ex1};
          const short8_t fy[4] = {gy0, gy1, ey0, ey1};
          layerK128R2(aX, aY, fx, fy, sW + OFF_W71, l);
        }
        scatterN_relu(BUF0, aX, q, n);
        scatterN_relu(BUF1, aY, q, n);
        floatx4 bX[4], bY[4];
        init_accL(bX, sConst + CB72, n); init_accL(bY, sConst + CB72, n);
        {
          const short8_t gx0 = ldN(BUF0, l), gx1 = ldN(BUF0, 64 + l);
          const short8_t gy0 = ldN(BUF1, l), gy1 = ldN(BUF1, 64 + l);
          layerK64R2<2>(bX, bY, gx0, gx1, gy0, gy1, sW + OFF_W72, l);
        }
        scatterN_relu(BUF0, bX, q, n);
        scatterN_relu(BUF1, bY, q, n);
        floatx4 cX[4], cY[4];
        init_accL(cX, sConst + CB73, n); init_accL(cY, sConst + CB73, n);
        {
          const short8_t gx0 = ldN(BUF0, l), gx1 = ldN(BUF0, 64 + l);
          const short8_t gy0 = ldN(BUF1, l), gy1 = ldN(BUF1, 64 + l);
          layerK64R2<2>(cX, cY, gx0, gx1, gy0, gy1, sW + OFF_W73, l);
        }

        if (it == 0) {
          scatterN_relu(BUF0, cX, q, n);   // new e (cross-lane -> LDS)
          scatterN_relu(BUF1, cY, q, n);
        } else {
          epilogue(cX, sConst, p.out, g0X, q, n, true);
          epilogue(cY, sConst, p.out, g0Y, q, n, okY);
        }
      }
    }
  }
}

extern "C" void kernel_launch(void* const* d_in, const int* in_sizes, int n_in,
                              void* d_out, int out_size, void* d_ws, size_t ws_size,
                              hipStream_t stream) {
  Params p;
  p.ap    = (const float*)d_in[0];
  p.ef    = (const float*)d_in[1];
  p.wpa   = (const float*)d_in[2];  p.bpa   = (const float*)d_in[3];
  p.wpe   = (const float*)d_in[4];  p.bpe   = (const float*)d_in[5];
  p.w51   = (const float*)d_in[6];  p.b51   = (const float*)d_in[7];
  p.w52   = (const float*)d_in[8];  p.b52   = (const float*)d_in[9];
  p.w53   = (const float*)d_in[10]; p.b53   = (const float*)d_in[11];
  p.w61   = (const float*)d_in[12]; p.b61   = (const float*)d_in[13];
  p.w62   = (const float*)d_in[14]; p.b62   = (const float*)d_in[15];
  p.w63   = (const float*)d_in[16]; p.b63   = (const float*)d_in[17];
  p.w71   = (const float*)d_in[18]; p.b71   = (const float*)d_in[19];
  p.w72   = (const float*)d_in[20]; p.b72   = (const float*)d_in[21];
  p.w73   = (const float*)d_in[22]; p.b73   = (const float*)d_in[23];
  p.wpost = (const float*)d_in[24]; p.bpost = (const float*)d_in[25];
  p.out   = (float*)d_out;
  p.gtot  = in_sizes[0] / 4;  // G from ap_feat [G,B,1]

  hipLaunchKernelGGL(hetgnn_mfma, dim3(NBLK), dim3(512), 0, stream, p);
}

// Round 16
// 154.382 us; speedup vs baseline: 1.0508x; 1.0090x over previous
//
#include <hip/hip_runtime.h>

// HetGNN fused kernel, round 30: R27 body (best: 57.8 us/dispatch) +
// s_setprio around MFMA clusters (T5).
// R28/R29 post-mortems: single-chain (R28) exposed LDS round-trip latency
// (-26 us); MFMA-for-VALU trade (R29) showed build_h's VALU was issuing in
// latency shadow (time tracked the ADDED MFMA, ignored the deleted VALU).
// => R27 is a local optimum; residual gap to the ~27us VALU floor is exposed
// scatter->gather latency; more waves (LDS) and more streams (VGPR) are
// walls. Untried matching lever: T5 s_setprio -- null on barrier-lockstep
// kernels, +4-7% where waves sit at different phases (m191). Our main loop
// has NO barriers: 16 desynchronized waves/CU, 2 chains each -- the
// arbitration-rich regime. Wrap each layer's MFMA cluster in setprio(1)/(0).
// Everything else byte-identical to R27 (pi0 layout, dual chain, pk2 pack,
// LDSFENCE discipline, 512 thr, (2,2), 112 VGPR no-spill).

typedef unsigned short u16;
typedef unsigned int   u32;
typedef __attribute__((ext_vector_type(8))) short short8_t;
typedef __attribute__((ext_vector_type(2))) short short2v;
typedef __attribute__((ext_vector_type(4))) float floatx4;

#define LDSFENCE() asm volatile("" ::: "memory")

// u16 offsets of each matrix's fragment block inside sW (fi*512 ordering).
// 96 frags: w51(16) w61(16) w71(16) w52(8) w53(8) w62(8) w63(8) w72(8) w73(8).
#define OFF_W51 0
#define OFF_W61 8192
#define OFF_W71 16384
#define OFF_W52 24576
#define OFF_W53 28672
#define OFF_W62 32768
#define OFF_W63 36864
#define OFF_W72 40960
#define OFF_W73 45056
#define WS_U16  49152

// f32 offsets inside the sConst LDS table.
#define CB51 0
#define CB52 64
#define CB53 128
#define CB61 192
#define CB62 256
#define CB63 320
#define CB71 384
#define CB72 448
#define CB73 512
#define CWPO 576
#define CBPO 704
#define CWPA 768
#define CBPA 832
#define CWPE 896
#define CBPE 1024
#define CSZ  1088

// new-layout tiles: BUF 128 rows -> 1080 u16 (pad 1088); aPb 64 rows -> 536 (pad 544)
#define BUF_U16 1088
#define APB_U16 544
#define PW_U16  3264   // 2 chains x (BUF | aPb)

struct Params {
  const float *ap, *ef;
  const float *wpa, *bpa, *wpe, *bpe;
  const float *w51, *b51, *w52, *b52, *w53, *b53;
  const float *w61, *b61, *w62, *b62, *w63, *b63;
  const float *w71, *b71, *w72, *b72, *w73, *b73;
  const float *wpost, *bpost;
  float *out;
  int gtot;
};

// Pack two f32 to bf16 pair: round-half-up via +0x8000, then one byte-perm.
// Low half = first arg. (PROVEN form; v_cvt_pk_bf16_f32 asm fails here.)
__device__ __forceinline__ u32 pk2(float a, float b) {
  const u32 ua = __float_as_uint(a) + 0x8000u;
  const u32 ub = __float_as_uint(b) + 0x8000u;
  return __builtin_amdgcn_perm(ub, ua, 0x07060302u);  // {ub[31:16], ua[31:16]}
}
__device__ __forceinline__ float blo(u32 v) { return __uint_as_float(v << 16); }
__device__ __forceinline__ float bhi(u32 v) { return __uint_as_float(v & 0xffff0000u); }
// packed int16 max: exact bf16-max in our use because the final max-with-0
// (deferred relu) dominates any mis-ordered negative intermediate.
__device__ __forceinline__ u32 pkmax(u32 a, u32 b) {
  const short2v r = __builtin_elementwise_max(__builtin_bit_cast(short2v, a),
                                              __builtin_bit_cast(short2v, b));
  return __builtin_bit_cast(u32, r);
}
__device__ __forceinline__ float sel4(int i, float x0, float x1, float x2, float x3) {
  const float lo = (i & 1) ? x1 : x0;
  const float hi = (i & 1) ? x3 : x2;
  return (i & 2) ? hi : lo;
}

__device__ __forceinline__ floatx4 mfma16(short8_t a, short8_t b, floatx4 c) {
  return __builtin_amdgcn_mfma_f32_16x16x32_bf16(a, b, c, 0, 0, 0);
}
// tile row start (u16 index): row*16B + 16B skew per 16 rows
__device__ __forceinline__ int rowN(int row) { return row * 8 + (row >> 4) * 8; }
// tile gather: loads through uint4 (int family) so it orders against the
// u32 scatters under TBAA.
__device__ __forceinline__ short8_t ldN(const u16* buf, int row) {
  const uint4 v = *(const uint4*)(buf + rowN(row));
  return __builtin_bit_cast(short8_t, v);
}
__device__ __forceinline__ uint4 ldN4(const u16* buf, int row) {
  return *(const uint4*)(buf + rowN(row));
}

// Dual-chain K=64 layer: each B fragment is loaded ONCE and feeds both
// chains. setprio(1) keeps the matrix pipe fed while other waves load (T5).
template<int TSTRIDE>
__device__ __forceinline__ void layerK64R2(floatx4* aX, floatx4* aY,
                                           short8_t x0, short8_t x1,
                                           short8_t y0, short8_t y1,
                                           const u16* B, int l) {
  __builtin_amdgcn_s_setprio(1);
#pragma unroll
  for (int t = 0; t < 4; ++t) {
    const short8_t b0 = *(const short8_t*)(B + (t * TSTRIDE + 0) * 512 + l * 8);
    const short8_t b1 = *(const short8_t*)(B + (t * TSTRIDE + 1) * 512 + l * 8);
    aX[t] = mfma16(x0, b0, aX[t]);
    aY[t] = mfma16(y0, b0, aY[t]);
    aX[t] = mfma16(x1, b1, aX[t]);
    aY[t] = mfma16(y1, b1, aY[t]);
  }
  __builtin_amdgcn_s_setprio(0);
}

// Dual-chain K=128 layer (4 A-frags per chain), shared B loads.
__device__ __forceinline__ void layerK128R2(floatx4* aX, floatx4* aY,
                                            const short8_t* fx, const short8_t* fy,
                                            const u16* B, int l) {
  __builtin_amdgcn_s_setprio(1);
#pragma unroll
  for (int t = 0; t < 4; ++t)
#pragma unroll
    for (int h = 0; h < 4; ++h) {
      const short8_t b = *(const short8_t*)(B + (t * 4 + h) * 512 + l * 8);
      aX[t] = mfma16(fx[h], b, aX[t]);
      aY[t] = mfma16(fy[h], b, aY[t]);
    }
  __builtin_amdgcn_s_setprio(0);
}

// pi0 scatter: u32 (tp, r) from lane (q,n) -> row tp*64 + g*16 + 4q + r,
// dword n&3. relu via packed pkmax0. 8 ds_write_b32, 2 lanes/bank.
__device__ __forceinline__ void scatterN_relu(u16* dst, const floatx4* acc, int q, int n) {
  u32* d32 = (u32*)dst;
  const int g = n >> 2, d = n & 3;
#pragma unroll
  for (int tp = 0; tp < 2; ++tp)
#pragma unroll
    for (int r = 0; r < 4; ++r) {
      const int row = tp * 64 + g * 16 + 4 * q + r;
      d32[row * 4 + (row >> 4) * 4 + d] =
          pkmax(pk2(acc[2 * tp + 0][r], acc[2 * tp + 1][r]), 0u);
    }
  LDSFENCE();
}
// same, raw pack (eP can be negative; relu deferred).
__device__ __forceinline__ void scatterN_raw(u16* dst, const floatx4* acc, int q, int n) {
  u32* d32 = (u32*)dst;
  const int g = n >> 2, d = n & 3;
#pragma unroll
  for (int tp = 0; tp < 2; ++tp)
#pragma unroll
    for (int r = 0; r < 4; ++r) {
      const int row = tp * 64 + g * 16 + 4 * q + r;
      d32[row * 4 + (row >> 4) * 4 + d] = pk2(acc[2 * tp + 0][r], acc[2 * tp + 1][r]);
    }
  LDSFENCE();
}
// scatter of pre-packed u32s (v[tp*4+r]).
__device__ __forceinline__ void scatterN_u32(u16* dst, const u32* v, int q, int n) {
  u32* d32 = (u32*)dst;
  const int g = n >> 2, d = n & 3;
#pragma unroll
  for (int tp = 0; tp < 2; ++tp)
#pragma unroll
    for (int r = 0; r < 4; ++r) {
      const int row = tp * 64 + g * 16 + 4 * q + r;
      d32[row * 4 + (row >> 4) * 4 + d] = v[tp * 4 + r];
    }
  LDSFENCE();
}

// aP: k-dedup new-layout scatter (even graph rows only; rows 4q+rr and
// 4q+rr+1 are k-duplicates), b61 folded per-feat. Dedup row' = full_row>>1.
__device__ __forceinline__ void scatter_aP(u16* dst, const floatx4* acc, int q, int n,
                                           const float* cb61) {
  u32* d32 = (u32*)dst;
  const int g = n >> 2, d = n & 3;
#pragma unroll
  for (int tp = 0; tp < 2; ++tp) {
    const float bv0 = cb61[32 * tp + n];        // feat of acc[2tp]   = 32tp+n
    const float bv1 = cb61[32 * tp + 16 + n];   // feat of acc[2tp+1] = 32tp+16+n
#pragma unroll
    for (int rh = 0; rh < 2; ++rh) {            // rr = 2*rh (even rows)
      const int row = tp * 32 + g * 8 + 2 * q + rh;
      d32[row * 4 + (row >> 4) * 4 + d] =
          pk2(acc[2 * tp + 0][2 * rh] + bv0, acc[2 * tp + 1][2 * rh] + bv1);
    }
  }
  LDSFENCE();
}

__device__ __forceinline__ void init_accL(floatx4* acc, const float* cb, int n) {
#pragma unroll
  for (int t = 0; t < 4; ++t) {
    const float b = cb[16 * t + n];
    floatx4 v; v[0] = b; v[1] = b; v[2] = b; v[3] = b;
    acc[t] = v;
  }
}
__device__ __forceinline__ void init_acc0(floatx4* acc) {
#pragma unroll
  for (int t = 0; t < 4; ++t) { acc[t][0] = 0.f; acc[t][1] = 0.f; acc[t][2] = 0.f; acc[t][3] = 0.f; }
}

struct frag2 { short8_t f0, f1; };

__device__ __forceinline__ frag2 make_a(float apv, int q, const float* sc) {
  frag2 r;
#pragma unroll
  for (int h = 0; h < 2; ++h) {
    const int fb = 32 * h + 8 * q;
    const float4 wa0 = *(const float4*)(sc + CWPA + fb);
    const float4 wa1 = *(const float4*)(sc + CWPA + fb + 4);
    const float4 ba0 = *(const float4*)(sc + CBPA + fb);
    const float4 ba1 = *(const float4*)(sc + CBPA + fb + 4);
    uint4 pa;
    pa.x = pk2(fmaxf(fmaf(apv, wa0.x, ba0.x), 0.f), fmaxf(fmaf(apv, wa0.y, ba0.y), 0.f));
    pa.y = pk2(fmaxf(fmaf(apv, wa0.z, ba0.z), 0.f), fmaxf(fmaf(apv, wa0.w, ba0.w), 0.f));
    pa.z = pk2(fmaxf(fmaf(apv, wa1.x, ba1.x), 0.f), fmaxf(fmaf(apv, wa1.y, ba1.y), 0.f));
    pa.w = pk2(fmaxf(fmaf(apv, wa1.z, ba1.z), 0.f), fmaxf(fmaf(apv, wa1.w, ba1.w), 0.f));
    if (h == 0) r.f0 = __builtin_bit_cast(short8_t, pa);
    else        r.f1 = __builtin_bit_cast(short8_t, pa);
  }
  return r;
}

// Pre-layer for one chain (tables are pi0-permuted at staging).
__device__ __forceinline__ void prelayer(frag2& A, short8_t& e0, short8_t& e1,
                                         const Params& p, const float* sc,
                                         int g0, int q, int n) {
  const float apv = p.ap[(g0 + (n >> 3)) * 4 + ((n >> 1) & 3)];
  A = make_a(apv, q, sc);
  const float f0 = p.ef[(g0 + (n >> 3)) * 16 + (n & 7) * 2];
  const float f1 = p.ef[(g0 + (n >> 3)) * 16 + (n & 7) * 2 + 1];
#pragma unroll
  for (int h = 0; h < 2; ++h) {
    const int fb = 32 * h + 8 * q;
    const float4 w00 = *(const float4*)(sc + CWPE + fb);
    const float4 w01 = *(const float4*)(sc + CWPE + fb + 4);
    const float4 w10 = *(const float4*)(sc + CWPE + 64 + fb);
    const float4 w11 = *(const float4*)(sc + CWPE + 64 + fb + 4);
    const float4 be0 = *(const float4*)(sc + CBPE + fb);
    const float4 be1 = *(const float4*)(sc + CBPE + fb + 4);
    uint4 pe;
    pe.x = pk2(fmaxf(fmaf(f0, w00.x, fmaf(f1, w10.x, be0.x)), 0.f),
               fmaxf(fmaf(f0, w00.y, fmaf(f1, w10.y, be0.y)), 0.f));
    pe.y = pk2(fmaxf(fmaf(f0, w00.z, fmaf(f1, w10.z, be0.z)), 0.f),
               fmaxf(fmaf(f0, w00.w, fmaf(f1, w10.w, be0.w)), 0.f));
    pe.z = pk2(fmaxf(fmaf(f0, w01.x, fmaf(f1, w11.x, be1.x)), 0.f),
               fmaxf(fmaf(f0, w01.y, fmaf(f1, w11.y, be1.y)), 0.f));
    pe.w = pk2(fmaxf(fmaf(f0, w01.z, fmaf(f1, w11.z, be1.z)), 0.f),
               fmaxf(fmaf(f0, w01.w, fmaf(f1, w11.w, be1.w)), 0.f));
    if (h == 0) e0 = __builtin_bit_cast(short8_t, pe);
    else        e1 = __builtin_bit_cast(short8_t, pe);
  }
}

// Build the 3 neighbor-tile h fragments for one chain, all-pi0 layout:
// own aP (dedup rows) + neighbor eP (fragment rows of lane 16q+re).
__device__ __forceinline__ void build_h(short8_t* hf0, short8_t* hf1,
                                        const u16* aPb, const u16* BUF,
                                        int q, int n) {
  const int b_ln = (n >> 1) & 3;
  const int ar = 8 * q + (n >> 1);
  const uint4 av0 = ldN4(aPb, ar);
  const uint4 av1 = ldN4(aPb, 32 + ar);
#pragma unroll
  for (int j = 0; j < 3; ++j) {
    const int bp = j + (j >= b_ln);   // j-th neighbor of b_ln
    const int re = (n & 8) + bp * 2 + (n & 1);
    const uint4 ev0 = ldN4(BUF, 16 * q + re);
    const uint4 ev1 = ldN4(BUF, 64 + 16 * q + re);
    uint4 p0, p1;
    p0.x = pk2(fmaxf(blo(av0.x) + blo(ev0.x), 0.f), fmaxf(bhi(av0.x) + bhi(ev0.x), 0.f));
    p0.y = pk2(fmaxf(blo(av0.y) + blo(ev0.y), 0.f), fmaxf(bhi(av0.y) + bhi(ev0.y), 0.f));
    p0.z = pk2(fmaxf(blo(av0.z) + blo(ev0.z), 0.f), fmaxf(bhi(av0.z) + bhi(ev0.z), 0.f));
    p0.w = pk2(fmaxf(blo(av0.w) + blo(ev0.w), 0.f), fmaxf(bhi(av0.w) + bhi(ev0.w), 0.f));
    p1.x = pk2(fmaxf(blo(av1.x) + blo(ev1.x), 0.f), fmaxf(bhi(av1.x) + bhi(ev1.x), 0.f));
    p1.y = pk2(fmaxf(blo(av1.y) + blo(ev1.y), 0.f), fmaxf(bhi(av1.y) + bhi(ev1.y), 0.f));
    p1.z = pk2(fmaxf(blo(av1.z) + blo(ev1.z), 0.f), fmaxf(bhi(av1.z) + bhi(ev1.z), 0.f));
    p1.w = pk2(fmaxf(blo(av1.w) + blo(ev1.w), 0.f), fmaxf(bhi(av1.w) + bhi(ev1.w), 0.f));
    hf0[j] = __builtin_bit_cast(short8_t, p0);
    hf1[j] = __builtin_bit_cast(short8_t, p1);
  }
}

// Post linear + per-(g,b) L2 row normalization for one chain.
__device__ __forceinline__ void epilogue(const floatx4* acc3, const float* sc,
                                         float* out, int g0, int q, int n, bool ok) {
  float prr[4] = {0.f, 0.f, 0.f, 0.f}, pii[4] = {0.f, 0.f, 0.f, 0.f};
#pragma unroll
  for (int t = 0; t < 4; ++t) {
    const float wr = sc[CWPO + (16 * t + n) * 2];
    const float wi = sc[CWPO + (16 * t + n) * 2 + 1];
#pragma unroll
    for (int r = 0; r < 4; ++r) {
      const float e = fmaxf(acc3[t][r], 0.f);
      prr[r] = fmaf(e, wr, prr[r]);
      pii[r] = fmaf(e, wi, pii[r]);
    }
  }
  const float bpR = sc[CBPO], bpI = sc[CBPO + 1];
#pragma unroll
  for (int r = 0; r < 4; ++r) {
#pragma unroll
    for (int off = 1; off < 16; off <<= 1) {
      prr[r] += __shfl_xor(prr[r], off, 16);
      pii[r] += __shfl_xor(pii[r], off, 16);
    }
    prr[r] += bpR;
    pii[r] += bpI;
  }
  const int r = n >> 1, c = n & 1, rp = r ^ 1;
  const float pr_r  = sel4(r,  prr[0], prr[1], prr[2], prr[3]);
  const float pi_r  = sel4(r,  pii[0], pii[1], pii[2], pii[3]);
  const float pr_rp = sel4(rp, prr[0], prr[1], prr[2], prr[3]);
  const float pi_rp = sel4(rp, pii[0], pii[1], pii[2], pii[3]);
  const float num = c ? pi_r : pr_r;
  const float n2  = pr_r * pr_r + pi_r * pi_r + pr_rp * pr_rp + pi_rp * pi_rp;
  if (ok && n < 8) out[g0 * 16 + (4 * q + r) * 2 + c] = num / sqrtf(n2);
}

#define NBLK 256
#define NWAVE 8
#define PPW  2   // 256 blk * 8 waves * 2 chains * 2 = 8192 pairs = 16384 graphs

__global__ __launch_bounds__(512, 2)
__attribute__((amdgpu_waves_per_eu(2, 2)))
void hetgnn_mfma(Params p) {
  __shared__ __align__(16) u16   sW[WS_U16];            // 96 KB weights
  __shared__ __align__(16) u16   sAct[NWAVE * PW_U16];  // 51 KB: 8 x 2 x (BUF|aPb)
  __shared__ __align__(16) float sConst[CSZ];           // 4.25 KB

  const int tid  = threadIdx.x;
  const int wave = tid >> 6;
  const int l    = tid & 63;
  const int q    = l >> 4;
  const int n    = l & 15;

  // ---- stage + swizzle weights (f32 global -> bf16 B-frag LDS), 96 frags.
  //      pi0 k-order for ALL mats.
  {
    for (int fi = wave; fi < 96; fi += NWAVE) {   // wave-uniform fi, 12/wave
      int t, h, mi;
      if (fi < 48) { mi = fi >> 4; const int loc = fi & 15; t = loc >> 2; h = loc & 3; }
      else { const int j = fi - 48; mi = 3 + (j >> 3); const int loc = j & 7; t = loc >> 1; h = loc & 1; }
      const float* W =
          (mi == 0) ? p.w51 : (mi == 1) ? p.w61 : (mi == 2) ? p.w71 :
          (mi == 3) ? p.w52 : (mi == 4) ? p.w53 : (mi == 5) ? p.w62 :
          (mi == 6) ? p.w63 : (mi == 7) ? p.w72 : p.w73;
      const int nn = 16 * t + n;
      float w[8];
#pragma unroll
      for (int jj = 0; jj < 8; ++jj) {
        const int kidx = (fi < 48)
            ? 64 * (h >> 1) + 32 * (h & 1) + (jj & 1) * 16 + 4 * q + (jj >> 1)
            : 32 * h + (jj & 1) * 16 + 4 * q + (jj >> 1);
        w[jj] = W[kidx * 64 + nn];
      }
      uint4 o;
      o.x = pk2(w[0], w[1]); o.y = pk2(w[2], w[3]);
      o.z = pk2(w[4], w[5]); o.w = pk2(w[6], w[7]);
      *(uint4*)(sW + fi * 512 + l * 8) = o;
    }
  }
  if (tid < 64) {
    sConst[CB51 + tid] = p.b51[tid];
    sConst[CB52 + tid] = p.b52[tid];
    sConst[CB53 + tid] = p.b53[tid];
    sConst[CB61 + tid] = p.b61[tid];
    sConst[CB62 + tid] = p.b62[tid];
    sConst[CB63 + tid] = p.b63[tid];
    sConst[CB71 + tid] = p.b71[tid];
    sConst[CB72 + tid] = p.b72[tid];
    sConst[CB73 + tid] = p.b73[tid];
    // pre-layer tables permuted to pi0 slot order:
    // slot s holds feat = 32*(s>>5) + (s&1)*16 + 4*((s>>3)&3) + ((s>>1)&3)
    const int feat = 32 * (tid >> 5) + (tid & 1) * 16 + 4 * ((tid >> 3) & 3) + ((tid >> 1) & 3);
    sConst[CWPA + tid] = p.wpa[feat];
    sConst[CBPA + tid] = p.bpa[feat];
    sConst[CBPE + tid] = p.bpe[feat];
  }
  if (tid < 128) {
    sConst[CWPO + tid] = p.wpost[tid];
    const int s = tid & 63;
    const int feat = 32 * (s >> 5) + (s & 1) * 16 + 4 * ((s >> 3) & 3) + ((s >> 1) & 3);
    sConst[CWPE + tid] = p.wpe[(tid >> 6) * 64 + feat];
  }
  if (tid < 2) sConst[CBPO + tid] = p.bpost[tid];
  __syncthreads();

  u16* BUF0 = sAct + wave * PW_U16;   // chain X: T1 = eP = Eb alias (pi0 tile)
  u16* aPb0 = BUF0 + BUF_U16;
  u16* BUF1 = aPb0 + APB_U16;         // chain Y
  u16* aPb1 = BUF1 + BUF_U16;

  const int wslot = blockIdx.x * NWAVE + wave;

#pragma unroll 1
  for (int pi = 0; pi < PPW; ++pi) {
    const int g0X = (wslot * 4 + 2 * pi) * 2;   // chain X: graphs g0X, g0X+1
    const int g0Y = g0X + 2;                    // chain Y: graphs g0Y, g0Y+1
    if (g0X + 2 > p.gtot) break;
    const bool okY = (g0Y + 2 <= p.gtot);
    const int gY  = okY ? g0Y : g0X;            // safe index for loads

    // ---------------- pre-layer, both chains ----------------
    frag2 AX, AY;
    short8_t ex0, ex1, ey0, ey1;
    prelayer(AX, ex0, ex1, p, sConst, g0X, q, n);
    prelayer(AY, ey0, ey1, p, sConst, gY,  q, n);

    // ---- aP = a @ w61[:64] (+ b61 pre-fold), dedup pi0 tile (it-invariant) ----
    {
      floatx4 aaX[4], aaY[4];
      init_acc0(aaX); init_acc0(aaY);
      layerK64R2<4>(aaX, aaY, AX.f0, AX.f1, AY.f0, AY.f1, sW + OFF_W61, l);
      scatter_aP(aPb0, aaX, q, n, sConst + CB61);
      scatter_aP(aPb1, aaY, q, n, sConst + CB61);
    }

    // ---------------- 2 shared-weight update iterations ----------------
#pragma unroll 1
    for (int it = 0; it < 2; ++it) {
      if (it == 1) {
        ex0 = ldN(BUF0, l); ex1 = ldN(BUF0, 64 + l);   // new e from it0
        ey0 = ldN(BUF1, l); ey1 = ldN(BUF1, 64 + l);
      }

      // ---- mlp5 -> m1 (tpair-packed raw bf16; relu deferred to agg) ----
      u32 m1pX[8], m1pY[8];
      {
        floatx4 aX[4], aY[4];
        init_accL(aX, sConst + CB51, n); init_accL(aY, sConst + CB51, n);
        const short8_t fx[4] = {AX.f0, AX.f1, ex0, ex1};
        const short8_t fy[4] = {AY.f0, AY.f1, ey0, ey1};
        layerK128R2(aX, aY, fx, fy, sW + OFF_W51, l);
        scatterN_relu(BUF0, aX, q, n);
        scatterN_relu(BUF1, aY, q, n);
        floatx4 bX[4], bY[4];
        init_accL(bX, sConst + CB52, n); init_accL(bY, sConst + CB52, n);
        {
          const short8_t gx0 = ldN(BUF0, l), gx1 = ldN(BUF0, 64 + l);
          const short8_t gy0 = ldN(BUF1, l), gy1 = ldN(BUF1, 64 + l);
          layerK64R2<2>(bX, bY, gx0, gx1, gy0, gy1, sW + OFF_W52, l);
        }
        scatterN_relu(BUF0, bX, q, n);
        scatterN_relu(BUF1, bY, q, n);
        floatx4 cX[4], cY[4];
        init_accL(cX, sConst + CB53, n); init_accL(cY, sConst + CB53, n);
        {
          const short8_t gx0 = ldN(BUF0, l), gx1 = ldN(BUF0, 64 + l);
          const short8_t gy0 = ldN(BUF1, l), gy1 = ldN(BUF1, 64 + l);
          layerK64R2<2>(cX, cY, gx0, gx1, gy0, gy1, sW + OFF_W53, l);
        }
#pragma unroll
        for (int tp = 0; tp < 2; ++tp)
#pragma unroll
          for (int r = 0; r < 4; ++r) {
            m1pX[tp * 4 + r] = pk2(cX[2 * tp][r], cX[2 * tp + 1][r]);
            m1pY[tp * 4 + r] = pk2(cY[2 * tp][r], cY[2 * tp + 1][r]);
          }
      }

      // ---- mlp6 -> m2: 3 neighbor-tiles; hf hoisted so eP (=BUF) dies
      //      before the first T1 (=BUF) scatter of the j-loop ----
      u32 m2pX[8], m2pY[8];
      {
        floatx4 eX[4], eY[4];
        init_acc0(eX); init_acc0(eY);
        layerK64R2<4>(eX, eY, ex0, ex1, ey0, ey1, sW + OFF_W61 + 2 * 512, l);
        scatterN_raw(BUF0, eX, q, n);   // eP, pi0 tile
        scatterN_raw(BUF1, eY, q, n);

        short8_t hfX0[3], hfX1[3], hfY0[3], hfY1[3];
        build_h(hfX0, hfX1, aPb0, BUF0, q, n);
        build_h(hfY0, hfY1, aPb1, BUF1, q, n);

#pragma unroll
        for (int j = 0; j < 3; ++j) {
          floatx4 uX[4], uY[4];
          init_accL(uX, sConst + CB62, n); init_accL(uY, sConst + CB62, n);
          layerK64R2<2>(uX, uY, hfX0[j], hfX1[j], hfY0[j], hfY1[j], sW + OFF_W62, l);
          scatterN_relu(BUF0, uX, q, n);
          scatterN_relu(BUF1, uY, q, n);
          floatx4 vX[4], vY[4];
          init_accL(vX, sConst + CB63, n); init_accL(vY, sConst + CB63, n);
          {
            const short8_t gx0 = ldN(BUF0, l), gx1 = ldN(BUF0, 64 + l);
            const short8_t gy0 = ldN(BUF1, l), gy1 = ldN(BUF1, 64 + l);
            layerK64R2<2>(vX, vY, gx0, gx1, gy0, gy1, sW + OFF_W63, l);
          }
#pragma unroll
          for (int tp = 0; tp < 2; ++tp)
#pragma unroll
            for (int r = 0; r < 4; ++r) {
              const u32 cXv = pk2(vX[2 * tp][r], vX[2 * tp + 1][r]);
              const u32 cYv = pk2(vY[2 * tp][r], vY[2 * tp + 1][r]);
              const int i = tp * 4 + r;
              m2pX[i] = (j == 0) ? cXv : pkmax(m2pX[i], cXv);
              m2pY[i] = (j == 0) ? cYv : pkmax(m2pY[i], cYv);
            }
        }
      }

      // ---- agg = relu(max(m1[k^1], m2)): k-swap is a register index swap ----
      {
        u32 agX[8], agY[8];
#pragma unroll
        for (int tp = 0; tp < 2; ++tp)
#pragma unroll
          for (int r = 0; r < 4; ++r) {
            const int i = tp * 4 + r;
            agX[i] = pkmax(pkmax(m1pX[tp * 4 + (r ^ 1)], m2pX[i]), 0u);
            agY[i] = pkmax(pkmax(m1pY[tp * 4 + (r ^ 1)], m2pY[i]), 0u);
          }
        scatterN_u32(BUF0, agX, q, n);
        scatterN_u32(BUF1, agY, q, n);
        floatx4 aX[4], aY[4];
        init_accL(aX, sConst + CB71, n); init_accL(aY, sConst + CB71, n);
        {
          const short8_t gx0 = ldN(BUF0, l), gx1 = ldN(BUF0, 64 + l);
          const short8_t gy0 = ldN(BUF1, l), gy1 = ldN(BUF1, 64 + l);
          const short8_t fx[4] = {gx0, gx1, ex0, ex1};
          const short8_t fy[4] = {gy0, gy1, ey0, ey1};
          layerK128R2(aX, aY, fx, fy, sW + OFF_W71, l);
        }
        scatterN_relu(BUF0, aX, q, n);
        scatterN_relu(BUF1, aY, q, n);
        floatx4 bX[4], bY[4];
        init_accL(bX, sConst + CB72, n); init_accL(bY, sConst + CB72, n);
        {
          const short8_t gx0 = ldN(BUF0, l), gx1 = ldN(BUF0, 64 + l);
          const short8_t gy0 = ldN(BUF1, l), gy1 = ldN(BUF1, 64 + l);
          layerK64R2<2>(bX, bY, gx0, gx1, gy0, gy1, sW + OFF_W72, l);
        }
        scatterN_relu(BUF0, bX, q, n);
        scatterN_relu(BUF1, bY, q, n);
        floatx4 cX[4], cY[4];
        init_accL(cX, sConst + CB73, n); init_accL(cY, sConst + CB73, n);
        {
          const short8_t gx0 = ldN(BUF0, l), gx1 = ldN(BUF0, 64 + l);
          const short8_t gy0 = ldN(BUF1, l), gy1 = ldN(BUF1, 64 + l);
          layerK64R2<2>(cX, cY, gx0, gx1, gy0, gy1, sW + OFF_W73, l);
        }

        if (it == 0) {
          scatterN_relu(BUF0, cX, q, n);   // new e (cross-lane -> LDS)
          scatterN_relu(BUF1, cY, q, n);
        } else {
          epilogue(cX, sConst, p.out, g0X, q, n, true);
          epilogue(cY, sConst, p.out, g0Y, q, n, okY);
        }
      }
    }
  }
}

extern "C" void kernel_launch(void* const* d_in, const int* in_sizes, int n_in,
                              void* d_out, int out_size, void* d_ws, size_t ws_size,
                              hipStream_t stream) {
  Params p;
  p.ap    = (const float*)d_in[0];
  p.ef    = (const float*)d_in[1];
  p.wpa   = (const float*)d_in[2];  p.bpa   = (const float*)d_in[3];
  p.wpe   = (const float*)d_in[4];  p.bpe   = (const float*)d_in[5];
  p.w51   = (const float*)d_in[6];  p.b51   = (const float*)d_in[7];
  p.w52   = (const float*)d_in[8];  p.b52   = (const float*)d_in[9];
  p.w53   = (const float*)d_in[10]; p.b53   = (const float*)d_in[11];
  p.w61   = (const float*)d_in[12]; p.b61   = (const float*)d_in[13];
  p.w62   = (const float*)d_in[14]; p.b62   = (const float*)d_in[15];
  p.w63   = (const float*)d_in[16]; p.b63   = (const float*)d_in[17];
  p.w71   = (const float*)d_in[18]; p.b71   = (const float*)d_in[19];
  p.w72   = (const float*)d_in[20]; p.b72   = (const float*)d_in[21];
  p.w73   = (const float*)d_in[22]; p.b73   = (const float*)d_in[23];
  p.wpost = (const float*)d_in[24]; p.bpost = (const float*)d_in[25];
  p.out   = (float*)d_out;
  p.gtot  = in_sizes[0] / 4;  // G from ap_feat [G,B,1]

  hipLaunchKernelGGL(hetgnn_mfma, dim3(NBLK), dim3(512), 0, stream, p);
}

// Round 17
// 149.634 us; speedup vs baseline: 1.0842x; 1.0317x over previous
//
#include <hip/hip_runtime.h>

// HetGNN fused kernel, FINAL (round 31 = R27 reverted, the measured best:
// 57.8 us/dispatch, 150.0 us bench, down from 166.3 at session start).
// R30's s_setprio was cleanly negative (+1.5 us: every wave boosting its own
// MFMA cluster creates no useful arbitration asymmetry); R28 (single-chain)
// and R29 (MFMA-for-VALU trade) both regressed. Probed-and-closed levers:
//  - occupancy: walled by 96KB resident weights + toolchain VGPR behavior;
//  - ILP: dual-chain load-bearing (R28: -26us without it); 3rd stream
//    doesn't fit the 128-VGPR cap;
//  - bank conflicts: 5.37M -> 1.5M with zero time effect -- not binding;
//  - glue VALU: pi0 machinery cut ~25% (real wins R25/R27); further cuts
//    sit in latency shadow (R29);
//  - scheduler hints: negative (R30).
// Residual profile: VALU 47% + MFMA 22% issue, ~30% exposed LDS round-trip
// latency at 2 waves/SIMD -- structural to "9 dependent 64-wide MLP layers
// through a lane-transposing LDS hop with all weights resident".
// Key verified facts baked in: pk2 (+0x8000/perm) is the working pack
// (v_cvt_pk_bf16_f32 asm FAILS on this target: R24/R26); u32 stores need
// int-family (uint4) loads + compiler fences for ordering (R24 vs R25);
// pi0 k-permutation makes row-pair u32 scatters and register k-swap exact.

typedef unsigned short u16;
typedef unsigned int   u32;
typedef __attribute__((ext_vector_type(8))) short short8_t;
typedef __attribute__((ext_vector_type(2))) short short2v;
typedef __attribute__((ext_vector_type(4))) float floatx4;

#define LDSFENCE() asm volatile("" ::: "memory")

// u16 offsets of each matrix's fragment block inside sW (fi*512 ordering).
// 96 frags: w51(16) w61(16) w71(16) w52(8) w53(8) w62(8) w63(8) w72(8) w73(8).
#define OFF_W51 0
#define OFF_W61 8192
#define OFF_W71 16384
#define OFF_W52 24576
#define OFF_W53 28672
#define OFF_W62 32768
#define OFF_W63 36864
#define OFF_W72 40960
#define OFF_W73 45056
#define WS_U16  49152

// f32 offsets inside the sConst LDS table.
#define CB51 0
#define CB52 64
#define CB53 128
#define CB61 192
#define CB62 256
#define CB63 320
#define CB71 384
#define CB72 448
#define CB73 512
#define CWPO 576
#define CBPO 704
#define CWPA 768
#define CBPA 832
#define CWPE 896
#define CBPE 1024
#define CSZ  1088

// new-layout tiles: BUF 128 rows -> 1080 u16 (pad 1088); aPb 64 rows -> 536 (pad 544)
#define BUF_U16 1088
#define APB_U16 544
#define PW_U16  3264   // 2 chains x (BUF | aPb)

struct Params {
  const float *ap, *ef;
  const float *wpa, *bpa, *wpe, *bpe;
  const float *w51, *b51, *w52, *b52, *w53, *b53;
  const float *w61, *b61, *w62, *b62, *w63, *b63;
  const float *w71, *b71, *w72, *b72, *w73, *b73;
  const float *wpost, *bpost;
  float *out;
  int gtot;
};

// Pack two f32 to bf16 pair: round-half-up via +0x8000, then one byte-perm.
// Low half = first arg. (PROVEN form; v_cvt_pk_bf16_f32 asm fails here.)
__device__ __forceinline__ u32 pk2(float a, float b) {
  const u32 ua = __float_as_uint(a) + 0x8000u;
  const u32 ub = __float_as_uint(b) + 0x8000u;
  return __builtin_amdgcn_perm(ub, ua, 0x07060302u);  // {ub[31:16], ua[31:16]}
}
__device__ __forceinline__ float blo(u32 v) { return __uint_as_float(v << 16); }
__device__ __forceinline__ float bhi(u32 v) { return __uint_as_float(v & 0xffff0000u); }
// packed int16 max: exact bf16-max in our use because the final max-with-0
// (deferred relu) dominates any mis-ordered negative intermediate.
__device__ __forceinline__ u32 pkmax(u32 a, u32 b) {
  const short2v r = __builtin_elementwise_max(__builtin_bit_cast(short2v, a),
                                              __builtin_bit_cast(short2v, b));
  return __builtin_bit_cast(u32, r);
}
__device__ __forceinline__ float sel4(int i, float x0, float x1, float x2, float x3) {
  const float lo = (i & 1) ? x1 : x0;
  const float hi = (i & 1) ? x3 : x2;
  return (i & 2) ? hi : lo;
}

__device__ __forceinline__ floatx4 mfma16(short8_t a, short8_t b, floatx4 c) {
  return __builtin_amdgcn_mfma_f32_16x16x32_bf16(a, b, c, 0, 0, 0);
}
// tile row start (u16 index): row*16B + 16B skew per 16 rows
__device__ __forceinline__ int rowN(int row) { return row * 8 + (row >> 4) * 8; }
// tile gather: loads through uint4 (int family) so it orders against the
// u32 scatters under TBAA.
__device__ __forceinline__ short8_t ldN(const u16* buf, int row) {
  const uint4 v = *(const uint4*)(buf + rowN(row));
  return __builtin_bit_cast(short8_t, v);
}
__device__ __forceinline__ uint4 ldN4(const u16* buf, int row) {
  return *(const uint4*)(buf + rowN(row));
}

// Dual-chain K=64 layer: each B fragment is loaded ONCE and feeds both chains.
template<int TSTRIDE>
__device__ __forceinline__ void layerK64R2(floatx4* aX, floatx4* aY,
                                           short8_t x0, short8_t x1,
                                           short8_t y0, short8_t y1,
                                           const u16* B, int l) {
#pragma unroll
  for (int t = 0; t < 4; ++t) {
    const short8_t b0 = *(const short8_t*)(B + (t * TSTRIDE + 0) * 512 + l * 8);
    const short8_t b1 = *(const short8_t*)(B + (t * TSTRIDE + 1) * 512 + l * 8);
    aX[t] = mfma16(x0, b0, aX[t]);
    aY[t] = mfma16(y0, b0, aY[t]);
    aX[t] = mfma16(x1, b1, aX[t]);
    aY[t] = mfma16(y1, b1, aY[t]);
  }
}

// Dual-chain K=128 layer (4 A-frags per chain), shared B loads.
__device__ __forceinline__ void layerK128R2(floatx4* aX, floatx4* aY,
                                            const short8_t* fx, const short8_t* fy,
                                            const u16* B, int l) {
#pragma unroll
  for (int t = 0; t < 4; ++t)
#pragma unroll
    for (int h = 0; h < 4; ++h) {
      const short8_t b = *(const short8_t*)(B + (t * 4 + h) * 512 + l * 8);
      aX[t] = mfma16(fx[h], b, aX[t]);
      aY[t] = mfma16(fy[h], b, aY[t]);
    }
}

// pi0 scatter: u32 (tp, r) from lane (q,n) -> row tp*64 + g*16 + 4q + r,
// dword n&3. relu via packed pkmax0. 8 ds_write_b32, 2 lanes/bank.
__device__ __forceinline__ void scatterN_relu(u16* dst, const floatx4* acc, int q, int n) {
  u32* d32 = (u32*)dst;
  const int g = n >> 2, d = n & 3;
#pragma unroll
  for (int tp = 0; tp < 2; ++tp)
#pragma unroll
    for (int r = 0; r < 4; ++r) {
      const int row = tp * 64 + g * 16 + 4 * q + r;
      d32[row * 4 + (row >> 4) * 4 + d] =
          pkmax(pk2(acc[2 * tp + 0][r], acc[2 * tp + 1][r]), 0u);
    }
  LDSFENCE();
}
// same, raw pack (eP can be negative; relu deferred).
__device__ __forceinline__ void scatterN_raw(u16* dst, const floatx4* acc, int q, int n) {
  u32* d32 = (u32*)dst;
  const int g = n >> 2, d = n & 3;
#pragma unroll
  for (int tp = 0; tp < 2; ++tp)
#pragma unroll
    for (int r = 0; r < 4; ++r) {
      const int row = tp * 64 + g * 16 + 4 * q + r;
      d32[row * 4 + (row >> 4) * 4 + d] = pk2(acc[2 * tp + 0][r], acc[2 * tp + 1][r]);
    }
  LDSFENCE();
}
// scatter of pre-packed u32s (v[tp*4+r]).
__device__ __forceinline__ void scatterN_u32(u16* dst, const u32* v, int q, int n) {
  u32* d32 = (u32*)dst;
  const int g = n >> 2, d = n & 3;
#pragma unroll
  for (int tp = 0; tp < 2; ++tp)
#pragma unroll
    for (int r = 0; r < 4; ++r) {
      const int row = tp * 64 + g * 16 + 4 * q + r;
      d32[row * 4 + (row >> 4) * 4 + d] = v[tp * 4 + r];
    }
  LDSFENCE();
}

// aP: k-dedup new-layout scatter (even graph rows only; rows 4q+rr and
// 4q+rr+1 are k-duplicates), b61 folded per-feat. Dedup row' = full_row>>1.
__device__ __forceinline__ void scatter_aP(u16* dst, const floatx4* acc, int q, int n,
                                           const float* cb61) {
  u32* d32 = (u32*)dst;
  const int g = n >> 2, d = n & 3;
#pragma unroll
  for (int tp = 0; tp < 2; ++tp) {
    const float bv0 = cb61[32 * tp + n];        // feat of acc[2tp]   = 32tp+n
    const float bv1 = cb61[32 * tp + 16 + n];   // feat of acc[2tp+1] = 32tp+16+n
#pragma unroll
    for (int rh = 0; rh < 2; ++rh) {            // rr = 2*rh (even rows)
      const int row = tp * 32 + g * 8 + 2 * q + rh;
      d32[row * 4 + (row >> 4) * 4 + d] =
          pk2(acc[2 * tp + 0][2 * rh] + bv0, acc[2 * tp + 1][2 * rh] + bv1);
    }
  }
  LDSFENCE();
}

__device__ __forceinline__ void init_accL(floatx4* acc, const float* cb, int n) {
#pragma unroll
  for (int t = 0; t < 4; ++t) {
    const float b = cb[16 * t + n];
    floatx4 v; v[0] = b; v[1] = b; v[2] = b; v[3] = b;
    acc[t] = v;
  }
}
__device__ __forceinline__ void init_acc0(floatx4* acc) {
#pragma unroll
  for (int t = 0; t < 4; ++t) { acc[t][0] = 0.f; acc[t][1] = 0.f; acc[t][2] = 0.f; acc[t][3] = 0.f; }
}

struct frag2 { short8_t f0, f1; };

__device__ __forceinline__ frag2 make_a(float apv, int q, const float* sc) {
  frag2 r;
#pragma unroll
  for (int h = 0; h < 2; ++h) {
    const int fb = 32 * h + 8 * q;
    const float4 wa0 = *(const float4*)(sc + CWPA + fb);
    const float4 wa1 = *(const float4*)(sc + CWPA + fb + 4);
    const float4 ba0 = *(const float4*)(sc + CBPA + fb);
    const float4 ba1 = *(const float4*)(sc + CBPA + fb + 4);
    uint4 pa;
    pa.x = pk2(fmaxf(fmaf(apv, wa0.x, ba0.x), 0.f), fmaxf(fmaf(apv, wa0.y, ba0.y), 0.f));
    pa.y = pk2(fmaxf(fmaf(apv, wa0.z, ba0.z), 0.f), fmaxf(fmaf(apv, wa0.w, ba0.w), 0.f));
    pa.z = pk2(fmaxf(fmaf(apv, wa1.x, ba1.x), 0.f), fmaxf(fmaf(apv, wa1.y, ba1.y), 0.f));
    pa.w = pk2(fmaxf(fmaf(apv, wa1.z, ba1.z), 0.f), fmaxf(fmaf(apv, wa1.w, ba1.w), 0.f));
    if (h == 0) r.f0 = __builtin_bit_cast(short8_t, pa);
    else        r.f1 = __builtin_bit_cast(short8_t, pa);
  }
  return r;
}

// Pre-layer for one chain (tables are pi0-permuted at staging).
__device__ __forceinline__ void prelayer(frag2& A, short8_t& e0, short8_t& e1,
                                         const Params& p, const float* sc,
                                         int g0, int q, int n) {
  const float apv = p.ap[(g0 + (n >> 3)) * 4 + ((n >> 1) & 3)];
  A = make_a(apv, q, sc);
  const float f0 = p.ef[(g0 + (n >> 3)) * 16 + (n & 7) * 2];
  const float f1 = p.ef[(g0 + (n >> 3)) * 16 + (n & 7) * 2 + 1];
#pragma unroll
  for (int h = 0; h < 2; ++h) {
    const int fb = 32 * h + 8 * q;
    const float4 w00 = *(const float4*)(sc + CWPE + fb);
    const float4 w01 = *(const float4*)(sc + CWPE + fb + 4);
    const float4 w10 = *(const float4*)(sc + CWPE + 64 + fb);
    const float4 w11 = *(const float4*)(sc + CWPE + 64 + fb + 4);
    const float4 be0 = *(const float4*)(sc + CBPE + fb);
    const float4 be1 = *(const float4*)(sc + CBPE + fb + 4);
    uint4 pe;
    pe.x = pk2(fmaxf(fmaf(f0, w00.x, fmaf(f1, w10.x, be0.x)), 0.f),
               fmaxf(fmaf(f0, w00.y, fmaf(f1, w10.y, be0.y)), 0.f));
    pe.y = pk2(fmaxf(fmaf(f0, w00.z, fmaf(f1, w10.z, be0.z)), 0.f),
               fmaxf(fmaf(f0, w00.w, fmaf(f1, w10.w, be0.w)), 0.f));
    pe.z = pk2(fmaxf(fmaf(f0, w01.x, fmaf(f1, w11.x, be1.x)), 0.f),
               fmaxf(fmaf(f0, w01.y, fmaf(f1, w11.y, be1.y)), 0.f));
    pe.w = pk2(fmaxf(fmaf(f0, w01.z, fmaf(f1, w11.z, be1.z)), 0.f),
               fmaxf(fmaf(f0, w01.w, fmaf(f1, w11.w, be1.w)), 0.f));
    if (h == 0) e0 = __builtin_bit_cast(short8_t, pe);
    else        e1 = __builtin_bit_cast(short8_t, pe);
  }
}

// Build the 3 neighbor-tile h fragments for one chain, all-pi0 layout:
// own aP (dedup rows) + neighbor eP (fragment rows of lane 16q+re).
__device__ __forceinline__ void build_h(short8_t* hf0, short8_t* hf1,
                                        const u16* aPb, const u16* BUF,
                                        int q, int n) {
  const int b_ln = (n >> 1) & 3;
  const int ar = 8 * q + (n >> 1);
  const uint4 av0 = ldN4(aPb, ar);
  const uint4 av1 = ldN4(aPb, 32 + ar);
#pragma unroll
  for (int j = 0; j < 3; ++j) {
    const int bp = j + (j >= b_ln);   // j-th neighbor of b_ln
    const int re = (n & 8) + bp * 2 + (n & 1);
    const uint4 ev0 = ldN4(BUF, 16 * q + re);
    const uint4 ev1 = ldN4(BUF, 64 + 16 * q + re);
    uint4 p0, p1;
    p0.x = pk2(fmaxf(blo(av0.x) + blo(ev0.x), 0.f), fmaxf(bhi(av0.x) + bhi(ev0.x), 0.f));
    p0.y = pk2(fmaxf(blo(av0.y) + blo(ev0.y), 0.f), fmaxf(bhi(av0.y) + bhi(ev0.y), 0.f));
    p0.z = pk2(fmaxf(blo(av0.z) + blo(ev0.z), 0.f), fmaxf(bhi(av0.z) + bhi(ev0.z), 0.f));
    p0.w = pk2(fmaxf(blo(av0.w) + blo(ev0.w), 0.f), fmaxf(bhi(av0.w) + bhi(ev0.w), 0.f));
    p1.x = pk2(fmaxf(blo(av1.x) + blo(ev1.x), 0.f), fmaxf(bhi(av1.x) + bhi(ev1.x), 0.f));
    p1.y = pk2(fmaxf(blo(av1.y) + blo(ev1.y), 0.f), fmaxf(bhi(av1.y) + bhi(ev1.y), 0.f));
    p1.z = pk2(fmaxf(blo(av1.z) + blo(ev1.z), 0.f), fmaxf(bhi(av1.z) + bhi(ev1.z), 0.f));
    p1.w = pk2(fmaxf(blo(av1.w) + blo(ev1.w), 0.f), fmaxf(bhi(av1.w) + bhi(ev1.w), 0.f));
    hf0[j] = __builtin_bit_cast(short8_t, p0);
    hf1[j] = __builtin_bit_cast(short8_t, p1);
  }
}

// Post linear + per-(g,b) L2 row normalization for one chain.
__device__ __forceinline__ void epilogue(const floatx4* acc3, const float* sc,
                                         float* out, int g0, int q, int n, bool ok) {
  float prr[4] = {0.f, 0.f, 0.f, 0.f}, pii[4] = {0.f, 0.f, 0.f, 0.f};
#pragma unroll
  for (int t = 0; t < 4; ++t) {
    const float wr = sc[CWPO + (16 * t + n) * 2];
    const float wi = sc[CWPO + (16 * t + n) * 2 + 1];
#pragma unroll
    for (int r = 0; r < 4; ++r) {
      const float e = fmaxf(acc3[t][r], 0.f);
      prr[r] = fmaf(e, wr, prr[r]);
      pii[r] = fmaf(e, wi, pii[r]);
    }
  }
  const float bpR = sc[CBPO], bpI = sc[CBPO + 1];
#pragma unroll
  for (int r = 0; r < 4; ++r) {
#pragma unroll
    for (int off = 1; off < 16; off <<= 1) {
      prr[r] += __shfl_xor(prr[r], off, 16);
      pii[r] += __shfl_xor(pii[r], off, 16);
    }
    prr[r] += bpR;
    pii[r] += bpI;
  }
  const int r = n >> 1, c = n & 1, rp = r ^ 1;
  const float pr_r  = sel4(r,  prr[0], prr[1], prr[2], prr[3]);
  const float pi_r  = sel4(r,  pii[0], pii[1], pii[2], pii[3]);
  const float pr_rp = sel4(rp, prr[0], prr[1], prr[2], prr[3]);
  const float pi_rp = sel4(rp, pii[0], pii[1], pii[2], pii[3]);
  const float num = c ? pi_r : pr_r;
  const float n2  = pr_r * pr_r + pi_r * pi_r + pr_rp * pr_rp + pi_rp * pi_rp;
  if (ok && n < 8) out[g0 * 16 + (4 * q + r) * 2 + c] = num / sqrtf(n2);
}

#define NBLK 256
#define NWAVE 8
#define PPW  2   // 256 blk * 8 waves * 2 chains * 2 = 8192 pairs = 16384 graphs

__global__ __launch_bounds__(512, 2)
__attribute__((amdgpu_waves_per_eu(2, 2)))
void hetgnn_mfma(Params p) {
  __shared__ __align__(16) u16   sW[WS_U16];            // 96 KB weights
  __shared__ __align__(16) u16   sAct[NWAVE * PW_U16];  // 51 KB: 8 x 2 x (BUF|aPb)
  __shared__ __align__(16) float sConst[CSZ];           // 4.25 KB

  const int tid  = threadIdx.x;
  const int wave = tid >> 6;
  const int l    = tid & 63;
  const int q    = l >> 4;
  const int n    = l & 15;

  // ---- stage + swizzle weights (f32 global -> bf16 B-frag LDS), 96 frags.
  //      pi0 k-order for ALL mats.
  {
    for (int fi = wave; fi < 96; fi += NWAVE) {   // wave-uniform fi, 12/wave
      int t, h, mi;
      if (fi < 48) { mi = fi >> 4; const int loc = fi & 15; t = loc >> 2; h = loc & 3; }
      else { const int j = fi - 48; mi = 3 + (j >> 3); const int loc = j & 7; t = loc >> 1; h = loc & 1; }
      const float* W =
          (mi == 0) ? p.w51 : (mi == 1) ? p.w61 : (mi == 2) ? p.w71 :
          (mi == 3) ? p.w52 : (mi == 4) ? p.w53 : (mi == 5) ? p.w62 :
          (mi == 6) ? p.w63 : (mi == 7) ? p.w72 : p.w73;
      const int nn = 16 * t + n;
      float w[8];
#pragma unroll
      for (int jj = 0; jj < 8; ++jj) {
        const int kidx = (fi < 48)
            ? 64 * (h >> 1) + 32 * (h & 1) + (jj & 1) * 16 + 4 * q + (jj >> 1)
            : 32 * h + (jj & 1) * 16 + 4 * q + (jj >> 1);
        w[jj] = W[kidx * 64 + nn];
      }
      uint4 o;
      o.x = pk2(w[0], w[1]); o.y = pk2(w[2], w[3]);
      o.z = pk2(w[4], w[5]); o.w = pk2(w[6], w[7]);
      *(uint4*)(sW + fi * 512 + l * 8) = o;
    }
  }
  if (tid < 64) {
    sConst[CB51 + tid] = p.b51[tid];
    sConst[CB52 + tid] = p.b52[tid];
    sConst[CB53 + tid] = p.b53[tid];
    sConst[CB61 + tid] = p.b61[tid];
    sConst[CB62 + tid] = p.b62[tid];
    sConst[CB63 + tid] = p.b63[tid];
    sConst[CB71 + tid] = p.b71[tid];
    sConst[CB72 + tid] = p.b72[tid];
    sConst[CB73 + tid] = p.b73[tid];
    // pre-layer tables permuted to pi0 slot order:
    // slot s holds feat = 32*(s>>5) + (s&1)*16 + 4*((s>>3)&3) + ((s>>1)&3)
    const int feat = 32 * (tid >> 5) + (tid & 1) * 16 + 4 * ((tid >> 3) & 3) + ((tid >> 1) & 3);
    sConst[CWPA + tid] = p.wpa[feat];
    sConst[CBPA + tid] = p.bpa[feat];
    sConst[CBPE + tid] = p.bpe[feat];
  }
  if (tid < 128) {
    sConst[CWPO + tid] = p.wpost[tid];
    const int s = tid & 63;
    const int feat = 32 * (s >> 5) + (s & 1) * 16 + 4 * ((s >> 3) & 3) + ((s >> 1) & 3);
    sConst[CWPE + tid] = p.wpe[(tid >> 6) * 64 + feat];
  }
  if (tid < 2) sConst[CBPO + tid] = p.bpost[tid];
  __syncthreads();

  u16* BUF0 = sAct + wave * PW_U16;   // chain X: T1 = eP = Eb alias (pi0 tile)
  u16* aPb0 = BUF0 + BUF_U16;
  u16* BUF1 = aPb0 + APB_U16;         // chain Y
  u16* aPb1 = BUF1 + BUF_U16;

  const int wslot = blockIdx.x * NWAVE + wave;

#pragma unroll 1
  for (int pi = 0; pi < PPW; ++pi) {
    const int g0X = (wslot * 4 + 2 * pi) * 2;   // chain X: graphs g0X, g0X+1
    const int g0Y = g0X + 2;                    // chain Y: graphs g0Y, g0Y+1
    if (g0X + 2 > p.gtot) break;
    const bool okY = (g0Y + 2 <= p.gtot);
    const int gY  = okY ? g0Y : g0X;            // safe index for loads

    // ---------------- pre-layer, both chains ----------------
    frag2 AX, AY;
    short8_t ex0, ex1, ey0, ey1;
    prelayer(AX, ex0, ex1, p, sConst, g0X, q, n);
    prelayer(AY, ey0, ey1, p, sConst, gY,  q, n);

    // ---- aP = a @ w61[:64] (+ b61 pre-fold), dedup pi0 tile (it-invariant) ----
    {
      floatx4 aaX[4], aaY[4];
      init_acc0(aaX); init_acc0(aaY);
      layerK64R2<4>(aaX, aaY, AX.f0, AX.f1, AY.f0, AY.f1, sW + OFF_W61, l);
      scatter_aP(aPb0, aaX, q, n, sConst + CB61);
      scatter_aP(aPb1, aaY, q, n, sConst + CB61);
    }

    // ---------------- 2 shared-weight update iterations ----------------
#pragma unroll 1
    for (int it = 0; it < 2; ++it) {
      if (it == 1) {
        ex0 = ldN(BUF0, l); ex1 = ldN(BUF0, 64 + l);   // new e from it0
        ey0 = ldN(BUF1, l); ey1 = ldN(BUF1, 64 + l);
      }

      // ---- mlp5 -> m1 (tpair-packed raw bf16; relu deferred to agg) ----
      u32 m1pX[8], m1pY[8];
      {
        floatx4 aX[4], aY[4];
        init_accL(aX, sConst + CB51, n); init_accL(aY, sConst + CB51, n);
        const short8_t fx[4] = {AX.f0, AX.f1, ex0, ex1};
        const short8_t fy[4] = {AY.f0, AY.f1, ey0, ey1};
        layerK128R2(aX, aY, fx, fy, sW + OFF_W51, l);
        scatterN_relu(BUF0, aX, q, n);
        scatterN_relu(BUF1, aY, q, n);
        floatx4 bX[4], bY[4];
        init_accL(bX, sConst + CB52, n); init_accL(bY, sConst + CB52, n);
        {
          const short8_t gx0 = ldN(BUF0, l), gx1 = ldN(BUF0, 64 + l);
          const short8_t gy0 = ldN(BUF1, l), gy1 = ldN(BUF1, 64 + l);
          layerK64R2<2>(bX, bY, gx0, gx1, gy0, gy1, sW + OFF_W52, l);
        }
        scatterN_relu(BUF0, bX, q, n);
        scatterN_relu(BUF1, bY, q, n);
        floatx4 cX[4], cY[4];
        init_accL(cX, sConst + CB53, n); init_accL(cY, sConst + CB53, n);
        {
          const short8_t gx0 = ldN(BUF0, l), gx1 = ldN(BUF0, 64 + l);
          const short8_t gy0 = ldN(BUF1, l), gy1 = ldN(BUF1, 64 + l);
          layerK64R2<2>(cX, cY, gx0, gx1, gy0, gy1, sW + OFF_W53, l);
        }
#pragma unroll
        for (int tp = 0; tp < 2; ++tp)
#pragma unroll
          for (int r = 0; r < 4; ++r) {
            m1pX[tp * 4 + r] = pk2(cX[2 * tp][r], cX[2 * tp + 1][r]);
            m1pY[tp * 4 + r] = pk2(cY[2 * tp][r], cY[2 * tp + 1][r]);
          }
      }

      // ---- mlp6 -> m2: 3 neighbor-tiles; hf hoisted so eP (=BUF) dies
      //      before the first T1 (=BUF) scatter of the j-loop ----
      u32 m2pX[8], m2pY[8];
      {
        floatx4 eX[4], eY[4];
        init_acc0(eX); init_acc0(eY);
        layerK64R2<4>(eX, eY, ex0, ex1, ey0, ey1, sW + OFF_W61 + 2 * 512, l);
        scatterN_raw(BUF0, eX, q, n);   // eP, pi0 tile
        scatterN_raw(BUF1, eY, q, n);

        short8_t hfX0[3], hfX1[3], hfY0[3], hfY1[3];
        build_h(hfX0, hfX1, aPb0, BUF0, q, n);
        build_h(hfY0, hfY1, aPb1, BUF1, q, n);

#pragma unroll
        for (int j = 0; j < 3; ++j) {
          floatx4 uX[4], uY[4];
          init_accL(uX, sConst + CB62, n); init_accL(uY, sConst + CB62, n);
          layerK64R2<2>(uX, uY, hfX0[j], hfX1[j], hfY0[j], hfY1[j], sW + OFF_W62, l);
          scatterN_relu(BUF0, uX, q, n);
          scatterN_relu(BUF1, uY, q, n);
          floatx4 vX[4], vY[4];
          init_accL(vX, sConst + CB63, n); init_accL(vY, sConst + CB63, n);
          {
            const short8_t gx0 = ldN(BUF0, l), gx1 = ldN(BUF0, 64 + l);
            const short8_t gy0 = ldN(BUF1, l), gy1 = ldN(BUF1, 64 + l);
            layerK64R2<2>(vX, vY, gx0, gx1, gy0, gy1, sW + OFF_W63, l);
          }
#pragma unroll
          for (int tp = 0; tp < 2; ++tp)
#pragma unroll
            for (int r = 0; r < 4; ++r) {
              const u32 cXv = pk2(vX[2 * tp][r], vX[2 * tp + 1][r]);
              const u32 cYv = pk2(vY[2 * tp][r], vY[2 * tp + 1][r]);
              const int i = tp * 4 + r;
              m2pX[i] = (j == 0) ? cXv : pkmax(m2pX[i], cXv);
              m2pY[i] = (j == 0) ? cYv : pkmax(m2pY[i], cYv);
            }
        }
      }

      // ---- agg = relu(max(m1[k^1], m2)): k-swap is a register index swap ----
      {
        u32 agX[8], agY[8];
#pragma unroll
        for (int tp = 0; tp < 2; ++tp)
#pragma unroll
          for (int r = 0; r < 4; ++r) {
            const int i = tp * 4 + r;
            agX[i] = pkmax(pkmax(m1pX[tp * 4 + (r ^ 1)], m2pX[i]), 0u);
            agY[i] = pkmax(pkmax(m1pY[tp * 4 + (r ^ 1)], m2pY[i]), 0u);
          }
        scatterN_u32(BUF0, agX, q, n);
        scatterN_u32(BUF1, agY, q, n);
        floatx4 aX[4], aY[4];
        init_accL(aX, sConst + CB71, n); init_accL(aY, sConst + CB71, n);
        {
          const short8_t gx0 = ldN(BUF0, l), gx1 = ldN(BUF0, 64 + l);
          const short8_t gy0 = ldN(BUF1, l), gy1 = ldN(BUF1, 64 + l);
          const short8_t fx[4] = {gx0, gx1, ex0, ex1};
          const short8_t fy[4] = {gy0, gy1, ey0, ey1};
          layerK128R2(aX, aY, fx, fy, sW + OFF_W71, l);
        }
        scatterN_relu(BUF0, aX, q, n);
        scatterN_relu(BUF1, aY, q, n);
        floatx4 bX[4], bY[4];
        init_accL(bX, sConst + CB72, n); init_accL(bY, sConst + CB72, n);
        {
          const short8_t gx0 = ldN(BUF0, l), gx1 = ldN(BUF0, 64 + l);
          const short8_t gy0 = ldN(BUF1, l), gy1 = ldN(BUF1, 64 + l);
          layerK64R2<2>(bX, bY, gx0, gx1, gy0, gy1, sW + OFF_W72, l);
        }
        scatterN_relu(BUF0, bX, q, n);
        scatterN_relu(BUF1, bY, q, n);
        floatx4 cX[4], cY[4];
        init_accL(cX, sConst + CB73, n); init_accL(cY, sConst + CB73, n);
        {
          const short8_t gx0 = ldN(BUF0, l), gx1 = ldN(BUF0, 64 + l);
          const short8_t gy0 = ldN(BUF1, l), gy1 = ldN(BUF1, 64 + l);
          layerK64R2<2>(cX, cY, gx0, gx1, gy0, gy1, sW + OFF_W73, l);
        }

        if (it == 0) {
          scatterN_relu(BUF0, cX, q, n);   // new e (cross-lane -> LDS)
          scatterN_relu(BUF1, cY, q, n);
        } else {
          epilogue(cX, sConst, p.out, g0X, q, n, true);
          epilogue(cY, sConst, p.out, g0Y, q, n, okY);
        }
      }
    }
  }
}

extern "C" void kernel_launch(void* const* d_in, const int* in_sizes, int n_in,
                              void* d_out, int out_size, void* d_ws, size_t ws_size,
                              hipStream_t stream) {
  Params p;
  p.ap    = (const float*)d_in[0];
  p.ef    = (const float*)d_in[1];
  p.wpa   = (const float*)d_in[2];  p.bpa   = (const float*)d_in[3];
  p.wpe   = (const float*)d_in[4];  p.bpe   = (const float*)d_in[5];
  p.w51   = (const float*)d_in[6];  p.b51   = (const float*)d_in[7];
  p.w52   = (const float*)d_in[8];  p.b52   = (const float*)d_in[9];
  p.w53   = (const float*)d_in[10]; p.b53   = (const float*)d_in[11];
  p.w61   = (const float*)d_in[12]; p.b61   = (const float*)d_in[13];
  p.w62   = (const float*)d_in[14]; p.b62   = (const float*)d_in[15];
  p.w63   = (const float*)d_in[16]; p.b63   = (const float*)d_in[17];
  p.w71   = (const float*)d_in[18]; p.b71   = (const float*)d_in[19];
  p.w72   = (const float*)d_in[20]; p.b72   = (const float*)d_in[21];
  p.w73   = (const float*)d_in[22]; p.b73   = (const float*)d_in[23];
  p.wpost = (const float*)d_in[24]; p.bpost = (const float*)d_in[25];
  p.out   = (float*)d_out;
  p.gtot  = in_sizes[0] / 4;  // G from ap_feat [G,B,1]

  hipLaunchKernelGGL(hetgnn_mfma, dim3(NBLK), dim3(512), 0, stream, p);
}